// Round 5
// baseline (231.347 us; speedup 1.0000x reference)
//
#include <hip/hip_runtime.h>
#include <math.h>

#define TOK   16384   // Bf * hw
#define HW    4096
#define C     128
#define D     64
#define HID   256

constexpr float LN_EPS = 1e-5f;
constexpr float EPS_R  = 1e-10f;
constexpr float QSCALE = 0.08838834764831845f; // 128^-0.5

typedef __attribute__((ext_vector_type(8))) short  bf16x8;
typedef __attribute__((ext_vector_type(4))) float  f32x4;
#define MFMA16(a, b, c) __builtin_amdgcn_mfma_f32_16x16x32_bf16((a), (b), (c), 0, 0, 0)

__device__ __forceinline__ float bflo(unsigned u) { return __uint_as_float(u << 16); }
__device__ __forceinline__ float bfhi(unsigned u) { return __uint_as_float(u & 0xffff0000u); }
__device__ __forceinline__ float bfu(unsigned short u) { return __uint_as_float((unsigned)u << 16); }
__device__ __forceinline__ unsigned short f2bf(float f) {
  unsigned u = __float_as_uint(f);
  unsigned r = (u + 0x7fffu + ((u >> 16) & 1u)) >> 16;
  return (unsigned short)r;
}
__device__ __forceinline__ float gelu_exact(float x) {
  return 0.5f * x * (1.0f + erff(x * 0.7071067811865476f));
}

// ---------------- K0: weight prep -> bf16, transposed Wt[n][k] --------------------
// layout in wt: [wqT 16384][wkT 16384][wvT 16384][pwT 16384][f1wT 32768][f2wT 32768]
__global__ __launch_bounds__(256) void k_prep(const float* __restrict__ wq,
    const float* __restrict__ wk, const float* __restrict__ wv,
    const float* __restrict__ pw, const float* __restrict__ f1w,
    const float* __restrict__ f2w, unsigned short* __restrict__ wt) {
  int id = blockIdx.x * 256 + threadIdx.x;
  if (id < 16384) {
    int n = id >> 7, k = id & 127;
    wt[id] = f2bf(wq[k * 128 + n]);
  } else if (id < 32768) {
    int e = id - 16384; int n = e >> 7, k = e & 127;
    wt[id] = f2bf(wk[k * 128 + n]);
  } else if (id < 49152) {
    int e = id - 32768; int n = e >> 7, k = e & 127;
    wt[id] = f2bf(wv[k * 128 + n]);
  } else if (id < 65536) {
    int e = id - 49152; int n = e >> 7, k = e & 127;
    wt[id] = f2bf(pw[k * 128 + n]);
  } else if (id < 98304) {
    int e = id - 65536; int n = e >> 7, k = e & 127;   // n in [0,256), k in [0,128)
    wt[id] = f2bf(f1w[k * 256 + n]);
  } else if (id < 131072) {
    int e = id - 98304; int n = e >> 8, k = e & 255;   // n in [0,128), k in [0,256)
    wt[id] = f2bf(f2w[k * 128 + n]);
  }
}

// ---------------- K1: transpose (NCHW -> token-major) + LayerNorm1 ----------------
__global__ __launch_bounds__(256) void k_ln1(const float* __restrict__ feat,
    const float* __restrict__ g, const float* __restrict__ b,
    unsigned short* __restrict__ xnb, float* __restrict__ xtm) {
  __shared__ float tile[64][C + 1];
  int t0 = blockIdx.x * 64;
  int n = t0 / HW, i0 = t0 % HW;
  int tid = threadIdx.x;
  const float* fb = feat + (size_t)n * C * HW;
  for (int e = tid; e < 64 * C; e += 256) {
    int ch = e >> 6, ii = e & 63;
    tile[ii][ch] = fb[(size_t)ch * HW + i0 + ii];
  }
  __syncthreads();
  int wave = tid >> 6, lane = tid & 63;
  for (int tkn = wave; tkn < 64; tkn += 4) {
    float a0 = tile[tkn][lane];
    float a1 = tile[tkn][lane + 64];
    float s = a0 + a1;
    for (int off = 32; off; off >>= 1) s += __shfl_xor(s, off, 64);
    float mean = s * (1.0f / 128.0f);
    float d0 = a0 - mean, d1 = a1 - mean;
    float v = d0 * d0 + d1 * d1;
    for (int off = 32; off; off >>= 1) v += __shfl_xor(v, off, 64);
    float rstd = rsqrtf(v * (1.0f / 128.0f) + LN_EPS);
    size_t ro = (size_t)(t0 + tkn) * C;
    xnb[ro + lane]      = f2bf(d0 * rstd * g[lane] + b[lane]);
    xnb[ro + lane + 64] = f2bf(d1 * rstd * g[lane + 64] + b[lane + 64]);
    xtm[ro + lane]      = a0;
    xtm[ro + lane + 64] = a1;
  }
}

// ---------------- K2: QKV GEMM via MFMA, col-split (by = wsel*2 + half) -----------
__global__ __launch_bounds__(256) void k_qkv(const unsigned short* __restrict__ xnb,
    const unsigned short* __restrict__ wt,
    const float* __restrict__ bq, const float* __restrict__ bk,
    const float* __restrict__ bv, float* __restrict__ q,
    unsigned short* __restrict__ ksw, unsigned short* __restrict__ vsw) {
  int w = threadIdx.x >> 6, lane = threadIdx.x & 63;
  int q4 = lane >> 4, m = lane & 15;
  int t0 = blockIdx.x * 64 + w * 16;
  int wsel = blockIdx.y >> 1, half = blockIdx.y & 1;
  const unsigned short* Wt = wt + wsel * 16384;
  const unsigned short* ap = xnb + (size_t)(t0 + m) * C + q4 * 8;
  bf16x8 a[4];
  #pragma unroll
  for (int ks = 0; ks < 4; ks++) a[ks] = *(const bf16x8*)(ap + ks * 32);
  f32x4 acc[4];
  #pragma unroll
  for (int nt = 0; nt < 4; nt++) acc[nt] = (f32x4){0.f, 0.f, 0.f, 0.f};
  #pragma unroll
  for (int nt = 0; nt < 4; nt++) {
    const unsigned short* bp = Wt + (size_t)(half * 64 + nt * 16 + m) * C + q4 * 8;
    #pragma unroll
    for (int ks = 0; ks < 4; ks++) {
      bf16x8 bfrag = *(const bf16x8*)(bp + ks * 32);
      acc[nt] = MFMA16(a[ks], bfrag, acc[nt]);
    }
  }
  if (wsel == 0) {
    #pragma unroll
    for (int nt = 0; nt < 4; nt++) {
      int col = half * 64 + nt * 16 + m;
      float bb = bq[col];
      #pragma unroll
      for (int reg = 0; reg < 4; reg++) {
        int row = t0 + q4 * 4 + reg;
        q[(size_t)row * C + col] = (acc[nt][reg] + bb) * QSCALE;
      }
    }
  } else {
    const float* B = (wsel == 1) ? bk : bv;
    unsigned short* O = (wsel == 1) ? ksw : vsw;
    int n = t0 >> 12, i0 = t0 & 4095;
    int tsw = ((n ^ 1) << 12) + i0;
    #pragma unroll
    for (int nt = 0; nt < 4; nt++) {
      int col = half * 64 + nt * 16 + m;
      float bb = B[col];
      #pragma unroll
      for (int reg = 0; reg < 4; reg++) {
        int row = tsw + q4 * 4 + reg;
        O[(size_t)row * C + col] = f2bf(acc[nt][reg] + bb);
      }
    }
  }
}

// ---------------- K3: gather attention (readlane broadcasts, XCD swizzle) ---------
__global__ __launch_bounds__(256) void k_attn(const float* __restrict__ q,
    const unsigned short* __restrict__ ksw, const unsigned short* __restrict__ vsw,
    const int* __restrict__ widx, const float* __restrict__ dprob,
    const float* __restrict__ kpe, const float* __restrict__ vpe,
    const float* __restrict__ rpe, unsigned short* __restrict__ aoutb) {
  int lane = threadIdx.x & 63;
  int wave = threadIdx.x >> 6;
  int bid = blockIdx.x;
  int n = (bid >> 1) & 3;
  int within = ((bid >> 3) << 1) | (bid & 1);
  int token = n * HW + within * 4 + wave;
  const unsigned short* Kb = ksw + (size_t)n * HW * C;
  const unsigned short* Vb = vsw + (size_t)n * HW * C;
  int g = lane >> 3, s = lane & 7;
  float qreg[16];
  const float* qp = q + (size_t)token * C + s * 16;
  #pragma unroll
  for (int i = 0; i < 4; i++) {
    float4 t = *(const float4*)(qp + i * 4);
    qreg[i * 4 + 0] = t.x; qreg[i * 4 + 1] = t.y;
    qreg[i * 4 + 2] = t.z; qreg[i * 4 + 3] = t.w;
  }
  float qpe = 0.f;
  #pragma unroll
  for (int i = 0; i < 16; i++) qpe += qreg[i];
  qpe += __shfl_xor(qpe, 1, 64);
  qpe += __shfl_xor(qpe, 2, 64);
  qpe += __shfl_xor(qpe, 4, 64);
  int myidx = widx[token * D + lane];
  float mydp = dprob[token * D + lane];
  float mycost = 0.f;
  #pragma unroll
  for (int pass = 0; pass < 8; ++pass) {
    int row = __shfl(myidx, pass * 8 + g, 64);
    const unsigned short* kr = Kb + (size_t)row * C + s * 16;
    uint4 ka = *(const uint4*)(kr);
    uint4 kb = *(const uint4*)(kr + 8);
    float p;
    p  = bflo(ka.x) * qreg[0]  + bfhi(ka.x) * qreg[1];
    p += bflo(ka.y) * qreg[2]  + bfhi(ka.y) * qreg[3];
    p += bflo(ka.z) * qreg[4]  + bfhi(ka.z) * qreg[5];
    p += bflo(ka.w) * qreg[6]  + bfhi(ka.w) * qreg[7];
    p += bflo(kb.x) * qreg[8]  + bfhi(kb.x) * qreg[9];
    p += bflo(kb.y) * qreg[10] + bfhi(kb.y) * qreg[11];
    p += bflo(kb.z) * qreg[12] + bfhi(kb.z) * qreg[13];
    p += bflo(kb.w) * qreg[14] + bfhi(kb.w) * qreg[15];
    p += __shfl_xor(p, 1, 64);
    p += __shfl_xor(p, 2, 64);
    p += __shfl_xor(p, 4, 64);
    float t = __shfl(p, (lane & 7) << 3, 64);
    if (pass == g) mycost = t;
  }
  mycost += qpe * kpe[lane] + rpe[lane];
  float mx = mycost;
  for (int off = 32; off; off >>= 1) mx = fmaxf(mx, __shfl_xor(mx, off, 64));
  float e = __expf(mycost - mx);
  float ssum = e;
  for (int off = 32; off; off >>= 1) ssum += __shfl_xor(ssum, off, 64);
  float attn = (e / ssum) * mydp;
  float s2 = attn;
  for (int off = 32; off; off >>= 1) s2 += __shfl_xor(s2, off, 64);
  attn = (attn + EPS_R) / (s2 + EPS_R);
  float vpt = attn * vpe[lane];
  for (int off = 32; off; off >>= 1) vpt += __shfl_xor(vpt, off, 64);
  float o0 = vpt, o1 = vpt;
  unsigned att_u = __float_as_uint(attn);
  #pragma unroll
  for (int kk = 0; kk < D; ++kk) {
    int row = __builtin_amdgcn_readlane(myidx, kk);
    float a = __uint_as_float(__builtin_amdgcn_readlane(att_u, kk));
    unsigned v = *(const unsigned*)(Vb + (size_t)row * C + lane * 2);
    o0 += a * bflo(v);
    o1 += a * bfhi(v);
  }
  unsigned pk = (unsigned)f2bf(o0) | ((unsigned)f2bf(o1) << 16);
  *(unsigned*)(aoutb + (size_t)token * C + lane * 2) = pk;
}

// ---------------- K4: proj GEMM (MFMA, col-split x2) + residual (in-place) --------
__global__ __launch_bounds__(256) void k_proj(const unsigned short* __restrict__ aoutb,
    const unsigned short* __restrict__ wt, const float* __restrict__ pb,
    float* xio) {
  int w = threadIdx.x >> 6, lane = threadIdx.x & 63;
  int q4 = lane >> 4, m = lane & 15;
  int t0 = blockIdx.x * 64 + w * 16;
  int half = blockIdx.y;
  const unsigned short* Wt = wt + 3 * 16384;  // pwT
  const unsigned short* ap = aoutb + (size_t)(t0 + m) * C + q4 * 8;
  bf16x8 a[4];
  #pragma unroll
  for (int ks = 0; ks < 4; ks++) a[ks] = *(const bf16x8*)(ap + ks * 32);
  f32x4 acc[4];
  #pragma unroll
  for (int nt = 0; nt < 4; nt++) acc[nt] = (f32x4){0.f, 0.f, 0.f, 0.f};
  #pragma unroll
  for (int nt = 0; nt < 4; nt++) {
    const unsigned short* bp = Wt + (size_t)(half * 64 + nt * 16 + m) * C + q4 * 8;
    #pragma unroll
    for (int ks = 0; ks < 4; ks++) {
      bf16x8 bfrag = *(const bf16x8*)(bp + ks * 32);
      acc[nt] = MFMA16(a[ks], bfrag, acc[nt]);
    }
  }
  #pragma unroll
  for (int nt = 0; nt < 4; nt++) {
    int col = half * 64 + nt * 16 + m;
    float bb = pb[col];
    #pragma unroll
    for (int reg = 0; reg < 4; reg++) {
      int row = t0 + q4 * 4 + reg;
      size_t ro = (size_t)row * C + col;
      xio[ro] = acc[nt][reg] + bb + xio[ro];
    }
  }
}

// ---------------- K5: LayerNorm2 (fp32 in, bf16 out) ------------------------------
__global__ __launch_bounds__(256) void k_ln2(const float* __restrict__ x,
    const float* __restrict__ g, const float* __restrict__ b,
    unsigned short* __restrict__ xn2b) {
  int wave = threadIdx.x >> 6, lane = threadIdx.x & 63;
  int tbase = blockIdx.x * 16 + wave * 4;
  for (int j = 0; j < 4; ++j) {
    size_t ro = (size_t)(tbase + j) * C;
    float a0 = x[ro + lane], a1 = x[ro + lane + 64];
    float s = a0 + a1;
    for (int off = 32; off; off >>= 1) s += __shfl_xor(s, off, 64);
    float mean = s * (1.0f / 128.0f);
    float d0 = a0 - mean, d1 = a1 - mean;
    float v = d0 * d0 + d1 * d1;
    for (int off = 32; off; off >>= 1) v += __shfl_xor(v, off, 64);
    float rstd = rsqrtf(v * (1.0f / 128.0f) + LN_EPS);
    xn2b[ro + lane]      = f2bf(d0 * rstd * g[lane] + b[lane]);
    xn2b[ro + lane + 64] = f2bf(d1 * rstd * g[lane + 64] + b[lane + 64]);
  }
}

// ---------------- K6: fc1 GEMM (MFMA, col-split x4) + GELU -> bf16 ----------------
__global__ __launch_bounds__(256) void k_fc1(const unsigned short* __restrict__ xn2b,
    const unsigned short* __restrict__ wt, const float* __restrict__ f1b,
    unsigned short* __restrict__ y) {
  int w = threadIdx.x >> 6, lane = threadIdx.x & 63;
  int q4 = lane >> 4, m = lane & 15;
  int t0 = blockIdx.x * 64 + w * 16;
  int cg = blockIdx.y;                      // col group: 64 cols each
  const unsigned short* Wf = wt + 65536;    // f1wT [256][128]
  const unsigned short* ap = xn2b + (size_t)(t0 + m) * C + q4 * 8;
  bf16x8 a[4];
  #pragma unroll
  for (int ks = 0; ks < 4; ks++) a[ks] = *(const bf16x8*)(ap + ks * 32);
  f32x4 acc[4];
  #pragma unroll
  for (int nt = 0; nt < 4; nt++) acc[nt] = (f32x4){0.f, 0.f, 0.f, 0.f};
  #pragma unroll
  for (int nt = 0; nt < 4; nt++) {
    const unsigned short* bp = Wf + (size_t)(cg * 64 + nt * 16 + m) * C + q4 * 8;
    #pragma unroll
    for (int ks = 0; ks < 4; ks++) {
      bf16x8 bfrag = *(const bf16x8*)(bp + ks * 32);
      acc[nt] = MFMA16(a[ks], bfrag, acc[nt]);
    }
  }
  #pragma unroll
  for (int nt = 0; nt < 4; nt++) {
    int col = cg * 64 + nt * 16 + m;
    float bb = f1b[col];
    #pragma unroll
    for (int reg = 0; reg < 4; reg++) {
      int row = t0 + q4 * 4 + reg;
      y[(size_t)row * HID + col] = f2bf(gelu_exact(acc[nt][reg] + bb));
    }
  }
}

// ---------------- K7: depthwise 5x5 conv + GELU (bf16, conflict-free LDS) ---------
__global__ __launch_bounds__(256) void k_dwconv(const unsigned short* __restrict__ y,
    const float* __restrict__ w, const float* __restrict__ bias,
    unsigned short* __restrict__ yc) {
  __shared__ float tile[8][401];   // [channel][spatial 20x20], odd stride: <=2-way
  __shared__ float wl[8][25];
  __shared__ float bl[8];
  int bid = blockIdx.x;
  int tile_id = bid & 15;
  int cb = (bid >> 4) & 31;
  int n = bid >> 9;
  int ty = (tile_id >> 2) * 16, tx = (tile_id & 3) * 16;
  int ch0 = cb * 8;
  int tid = threadIdx.x;
  if (tid < 200) wl[tid / 25][tid % 25] = w[(size_t)(ch0 + tid / 25) * 25 + tid % 25];
  if (tid < 8) bl[tid] = bias[ch0 + tid];
  const unsigned short* yb = y + (size_t)n * HW * HID;
  for (int e = tid; e < 400 * 8; e += 256) {
    int cc = e & 7;
    int p = e >> 3;
    int py = p / 20, px = p % 20;
    int gy = ty + py - 2, gx = tx + px - 2;
    float v = 0.f;
    if (gy >= 0 && gy < 64 && gx >= 0 && gx < 64)
      v = bfu(yb[(size_t)(gy * 64 + gx) * HID + ch0 + cc]);
    tile[cc][p] = v;
  }
  __syncthreads();
  int cc = tid & 7;
  int xx = (tid >> 3) & 15;
  int yg = tid >> 7;
  float wreg[25];
  #pragma unroll
  for (int k = 0; k < 25; k++) wreg[k] = wl[cc][k];
  float bb = bl[cc];
  for (int j = 0; j < 8; ++j) {
    int yy = yg * 8 + j;
    float acc = 0.f;
    #pragma unroll
    for (int dy = 0; dy < 5; ++dy)
      #pragma unroll
      for (int dx = 0; dx < 5; ++dx)
        acc += wreg[dy * 5 + dx] * tile[cc][(yy + dy) * 20 + (xx + dx)];
    acc = gelu_exact(acc + bb);
    yc[(size_t)(n * HW + (ty + yy) * 64 + tx + xx) * HID + ch0 + cc] = f2bf(acc);
  }
}

// ---------------- K8: fc2 GEMM (MFMA, col-split x2) on (y+yc) + residual ----------
__global__ __launch_bounds__(256) void k_fc2(const unsigned short* __restrict__ y,
    const unsigned short* __restrict__ ycg, const unsigned short* __restrict__ wt,
    const float* __restrict__ f2b, const float* __restrict__ xio,
    float* __restrict__ outp) {
  int w = threadIdx.x >> 6, lane = threadIdx.x & 63;
  int q4 = lane >> 4, m = lane & 15;
  int t0 = blockIdx.x * 64 + w * 16;
  int half = blockIdx.y;
  const unsigned short* Wt = wt + 98304;  // f2wT [128][256]
  const unsigned short* ap = y + (size_t)(t0 + m) * HID + q4 * 8;
  const unsigned short* cp = ycg + (size_t)(t0 + m) * HID + q4 * 8;
  union U { bf16x8 v; unsigned short s[8]; };
  bf16x8 a[8];
  #pragma unroll
  for (int ks = 0; ks < 8; ks++) {
    U ua, uc, ur;
    ua.v = *(const bf16x8*)(ap + ks * 32);
    uc.v = *(const bf16x8*)(cp + ks * 32);
    #pragma unroll
    for (int j = 0; j < 8; j++) ur.s[j] = f2bf(bfu(ua.s[j]) + bfu(uc.s[j]));
    a[ks] = ur.v;
  }
  f32x4 acc[4];
  #pragma unroll
  for (int nt = 0; nt < 4; nt++) acc[nt] = (f32x4){0.f, 0.f, 0.f, 0.f};
  #pragma unroll
  for (int nt = 0; nt < 4; nt++) {
    const unsigned short* bp = Wt + (size_t)(half * 64 + nt * 16 + m) * HID + q4 * 8;
    #pragma unroll
    for (int ks = 0; ks < 8; ks++) {
      bf16x8 bfrag = *(const bf16x8*)(bp + ks * 32);
      acc[nt] = MFMA16(a[ks], bfrag, acc[nt]);
    }
  }
  #pragma unroll
  for (int nt = 0; nt < 4; nt++) {
    int col = half * 64 + nt * 16 + m;
    float bb = f2b[col];
    #pragma unroll
    for (int reg = 0; reg < 4; reg++) {
      int row = t0 + q4 * 4 + reg;
      outp[(size_t)row * C + col] = acc[nt][reg] + bb + xio[(size_t)row * C + col];
    }
  }
}

extern "C" void kernel_launch(void* const* d_in, const int* in_sizes, int n_in,
                              void* d_out, int out_size, void* d_ws, size_t ws_size,
                              hipStream_t stream) {
  (void)in_sizes; (void)n_in; (void)out_size; (void)ws_size;
  const float* feat  = (const float*)d_in[0];
  const int*   widx  = (const int*)d_in[1];
  const float* dprob = (const float*)d_in[2];
  const float* ln1g  = (const float*)d_in[3];
  const float* ln1b  = (const float*)d_in[4];
  const float* wq    = (const float*)d_in[5];
  const float* bq    = (const float*)d_in[6];
  const float* wk    = (const float*)d_in[7];
  const float* bk    = (const float*)d_in[8];
  const float* wv    = (const float*)d_in[9];
  const float* bv    = (const float*)d_in[10];
  const float* kpe   = (const float*)d_in[11];
  const float* vpe   = (const float*)d_in[12];
  const float* rpe   = (const float*)d_in[13];
  const float* pw    = (const float*)d_in[14];
  const float* pb    = (const float*)d_in[15];
  const float* ln2g  = (const float*)d_in[16];
  const float* ln2b  = (const float*)d_in[17];
  const float* f1w   = (const float*)d_in[18];
  const float* f1b   = (const float*)d_in[19];
  const float* dww   = (const float*)d_in[20];
  const float* dwb   = (const float*)d_in[21];
  const float* f2w   = (const float*)d_in[22];
  const float* f2b   = (const float*)d_in[23];

  float* ws = (float*)d_ws;
  const size_t M2 = (size_t)TOK * C;  // 2,097,152 floats (8 MB)
  float* qb  = ws;                                                   // fp32 q (scaled)
  float* xio = ws + M2;                                              // fp32 residual stream
  unsigned short* xnb   = (unsigned short*)(ws + 2 * M2);            // bf16 ln1 out
  unsigned short* ksb   = (unsigned short*)(ws + 2 * M2 + M2 / 2);   // bf16 K (swapped)
  unsigned short* vsb   = (unsigned short*)(ws + 3 * M2);            // bf16 V (swapped)
  unsigned short* aoutb = (unsigned short*)(ws + 3 * M2 + M2 / 2);   // bf16 attn out
  unsigned short* xn2b  = (unsigned short*)(ws + 4 * M2);            // bf16 ln2 out
  unsigned short* yb    = (unsigned short*)(ws + 4 * M2 + M2 / 2);   // bf16 fc1 out (2*M2 ush)
  unsigned short* ycgb  = (unsigned short*)(ws + 5 * M2 + M2 / 2);   // bf16 dwconv out (2*M2 ush)
  unsigned short* wtb   = (unsigned short*)(ws + 6 * M2 + M2 / 2);   // bf16 weights (131072 ush)
  // total ≈ 6.5*M2*4 B + 256 KB ≈ 52.5 MB

  k_prep  <<<512, 256, 0, stream>>>(wq, wk, wv, pw, f1w, f2w, wtb);
  k_ln1   <<<TOK / 64, 256, 0, stream>>>(feat, ln1g, ln1b, xnb, xio);
  k_qkv   <<<dim3(TOK / 64, 6), 256, 0, stream>>>(xnb, wtb, bq, bk, bv, qb, ksb, vsb);
  k_attn  <<<TOK / 4, 256, 0, stream>>>(qb, ksb, vsb, widx, dprob, kpe, vpe, rpe, aoutb);
  k_proj  <<<dim3(TOK / 64, 2), 256, 0, stream>>>(aoutb, wtb, pb, xio);
  k_ln2   <<<TOK / 16, 256, 0, stream>>>(xio, ln2g, ln2b, xn2b);
  k_fc1   <<<dim3(TOK / 64, 4), 256, 0, stream>>>(xn2b, wtb, f1b, yb);
  k_dwconv<<<2048, 256, 0, stream>>>(yb, dww, dwb, ycgb);
  k_fc2   <<<dim3(TOK / 64, 2), 256, 0, stream>>>(yb, ycgb, wtb, f2b, xio, (float*)d_out);
}

// Round 6
// 217.317 us; speedup vs baseline: 1.0646x; 1.0646x over previous
//
#include <hip/hip_runtime.h>
#include <math.h>

#define TOK   16384   // Bf * hw
#define HW    4096
#define C     128
#define D     64
#define HID   256

constexpr float LN_EPS = 1e-5f;
constexpr float EPS_R  = 1e-10f;
constexpr float QSCALE = 0.08838834764831845f; // 128^-0.5

typedef __attribute__((ext_vector_type(8))) short  bf16x8;
typedef __attribute__((ext_vector_type(4))) float  f32x4;
#define MFMA16(a, b, c) __builtin_amdgcn_mfma_f32_16x16x32_bf16((a), (b), (c), 0, 0, 0)

__device__ __forceinline__ float bflo(unsigned u) { return __uint_as_float(u << 16); }
__device__ __forceinline__ float bfhi(unsigned u) { return __uint_as_float(u & 0xffff0000u); }
__device__ __forceinline__ float bfu(unsigned short u) { return __uint_as_float((unsigned)u << 16); }
__device__ __forceinline__ unsigned short f2bf(float f) {
  unsigned u = __float_as_uint(f);
  unsigned r = (u + 0x7fffu + ((u >> 16) & 1u)) >> 16;
  return (unsigned short)r;
}
__device__ __forceinline__ float gelu_exact(float x) {
  return 0.5f * x * (1.0f + erff(x * 0.7071067811865476f));
}

// ---------------- K0: weight prep -> bf16, transposed Wt[n][k] --------------------
__global__ __launch_bounds__(256) void k_prep(const float* __restrict__ wq,
    const float* __restrict__ wk, const float* __restrict__ wv,
    const float* __restrict__ pw, const float* __restrict__ f1w,
    const float* __restrict__ f2w, unsigned short* __restrict__ wt) {
  int id = blockIdx.x * 256 + threadIdx.x;
  if (id < 16384) {
    int n = id >> 7, k = id & 127;
    wt[id] = f2bf(wq[k * 128 + n]);
  } else if (id < 32768) {
    int e = id - 16384; int n = e >> 7, k = e & 127;
    wt[id] = f2bf(wk[k * 128 + n]);
  } else if (id < 49152) {
    int e = id - 32768; int n = e >> 7, k = e & 127;
    wt[id] = f2bf(wv[k * 128 + n]);
  } else if (id < 65536) {
    int e = id - 49152; int n = e >> 7, k = e & 127;
    wt[id] = f2bf(pw[k * 128 + n]);
  } else if (id < 98304) {
    int e = id - 65536; int n = e >> 7, k = e & 127;   // n in [0,256), k in [0,128)
    wt[id] = f2bf(f1w[k * 256 + n]);
  } else if (id < 131072) {
    int e = id - 98304; int n = e >> 8, k = e & 255;   // n in [0,128), k in [0,256)
    wt[id] = f2bf(f2w[k * 128 + n]);
  }
}

// ---------------- K1: transpose (NCHW -> token-major) + LayerNorm1 ----------------
__global__ __launch_bounds__(256) void k_ln1(const float* __restrict__ feat,
    const float* __restrict__ g, const float* __restrict__ b,
    unsigned short* __restrict__ xnb, float* __restrict__ xtm) {
  __shared__ float tile[64][C + 1];
  int t0 = blockIdx.x * 64;
  int n = t0 / HW, i0 = t0 % HW;
  int tid = threadIdx.x;
  const float* fb = feat + (size_t)n * C * HW;
  for (int e = tid; e < 64 * C; e += 256) {
    int ch = e >> 6, ii = e & 63;
    tile[ii][ch] = fb[(size_t)ch * HW + i0 + ii];
  }
  __syncthreads();
  int wave = tid >> 6, lane = tid & 63;
  for (int tkn = wave; tkn < 64; tkn += 4) {
    float a0 = tile[tkn][lane];
    float a1 = tile[tkn][lane + 64];
    float s = a0 + a1;
    for (int off = 32; off; off >>= 1) s += __shfl_xor(s, off, 64);
    float mean = s * (1.0f / 128.0f);
    float d0 = a0 - mean, d1 = a1 - mean;
    float v = d0 * d0 + d1 * d1;
    for (int off = 32; off; off >>= 1) v += __shfl_xor(v, off, 64);
    float rstd = rsqrtf(v * (1.0f / 128.0f) + LN_EPS);
    size_t ro = (size_t)(t0 + tkn) * C;
    xnb[ro + lane]      = f2bf(d0 * rstd * g[lane] + b[lane]);
    xnb[ro + lane + 64] = f2bf(d1 * rstd * g[lane + 64] + b[lane + 64]);
    xtm[ro + lane]      = a0;
    xtm[ro + lane + 64] = a1;
  }
}

// ---------------- K2: QKV GEMM via MFMA (blockIdx.y selects q/k/v) ----------------
__global__ __launch_bounds__(256) void k_qkv(const unsigned short* __restrict__ xnb,
    const unsigned short* __restrict__ wt,
    const float* __restrict__ bq, const float* __restrict__ bk,
    const float* __restrict__ bv, float* __restrict__ q,
    unsigned short* __restrict__ ksw, unsigned short* __restrict__ vsw) {
  int w = threadIdx.x >> 6, lane = threadIdx.x & 63;
  int q4 = lane >> 4, m = lane & 15;
  int t0 = blockIdx.x * 64 + w * 16;
  int wsel = blockIdx.y;
  const unsigned short* Wt = wt + wsel * 16384;
  const unsigned short* ap = xnb + (size_t)(t0 + m) * C + q4 * 8;
  bf16x8 a[4];
  #pragma unroll
  for (int ks = 0; ks < 4; ks++) a[ks] = *(const bf16x8*)(ap + ks * 32);
  f32x4 acc[8];
  #pragma unroll
  for (int nt = 0; nt < 8; nt++) acc[nt] = (f32x4){0.f, 0.f, 0.f, 0.f};
  #pragma unroll
  for (int nt = 0; nt < 8; nt++) {
    const unsigned short* bp = Wt + (size_t)(nt * 16 + m) * C + q4 * 8;
    #pragma unroll
    for (int ks = 0; ks < 4; ks++) {
      bf16x8 bfrag = *(const bf16x8*)(bp + ks * 32);
      acc[nt] = MFMA16(a[ks], bfrag, acc[nt]);
    }
  }
  if (wsel == 0) {
    #pragma unroll
    for (int nt = 0; nt < 8; nt++) {
      int col = nt * 16 + m;
      float bb = bq[col];
      #pragma unroll
      for (int reg = 0; reg < 4; reg++) {
        int row = t0 + q4 * 4 + reg;
        q[(size_t)row * C + col] = (acc[nt][reg] + bb) * QSCALE;
      }
    }
  } else {
    const float* B = (wsel == 1) ? bk : bv;
    unsigned short* O = (wsel == 1) ? ksw : vsw;
    int n = t0 >> 12, i0 = t0 & 4095;
    int tsw = ((n ^ 1) << 12) + i0;
    #pragma unroll
    for (int nt = 0; nt < 8; nt++) {
      int col = nt * 16 + m;
      float bb = B[col];
      #pragma unroll
      for (int reg = 0; reg < 4; reg++) {
        int row = tsw + q4 * 4 + reg;
        O[(size_t)row * C + col] = f2bf(acc[nt][reg] + bb);
      }
    }
  }
}

// ---------------- K3: gather attention (hoisted loads, readlane, XCD swizzle) -----
__global__ __launch_bounds__(256) void k_attn(const float* __restrict__ q,
    const unsigned short* __restrict__ ksw, const unsigned short* __restrict__ vsw,
    const int* __restrict__ widx, const float* __restrict__ dprob,
    const float* __restrict__ kpe, const float* __restrict__ vpe,
    const float* __restrict__ rpe, unsigned short* __restrict__ aoutb) {
  int lane = threadIdx.x & 63;
  int wave = threadIdx.x >> 6;
  // XCD swizzle: consecutive bid pairs rotate across views so each XCD's L2
  // mostly caches one view's K+V (2 MB < 4 MB L2).
  int bid = blockIdx.x;
  int n = (bid >> 1) & 3;
  int within = ((bid >> 3) << 1) | (bid & 1);
  int token = n * HW + within * 4 + wave;
  const unsigned short* Kb = ksw + (size_t)n * HW * C;
  const unsigned short* Vb = vsw + (size_t)n * HW * C;
  int g = lane >> 3, s = lane & 7;
  // hoisted per-lane inputs
  int myidx = widx[token * D + lane];
  float mydp = dprob[token * D + lane];
  float qreg[16];
  const float* qp = q + (size_t)token * C + s * 16;
  #pragma unroll
  for (int i = 0; i < 4; i++) {
    float4 t = *(const float4*)(qp + i * 4);
    qreg[i * 4 + 0] = t.x; qreg[i * 4 + 1] = t.y;
    qreg[i * 4 + 2] = t.z; qreg[i * 4 + 3] = t.w;
  }
  float qpe = 0.f;
  #pragma unroll
  for (int i = 0; i < 16; i++) qpe += qreg[i];
  qpe += __shfl_xor(qpe, 1, 64);
  qpe += __shfl_xor(qpe, 2, 64);
  qpe += __shfl_xor(qpe, 4, 64);
  // --- QmK: hoist all 8 row indices, then all 16 loads (MLP), then compute ---
  int rowv[8];
  #pragma unroll
  for (int pass = 0; pass < 8; ++pass)
    rowv[pass] = __shfl(myidx, pass * 8 + g, 64);
  uint4 ka[8], kb[8];
  #pragma unroll
  for (int pass = 0; pass < 8; ++pass) {
    const unsigned short* kr = Kb + (size_t)rowv[pass] * C + s * 16;
    ka[pass] = *(const uint4*)(kr);
    kb[pass] = *(const uint4*)(kr + 8);
  }
  float mycost = 0.f;
  #pragma unroll
  for (int pass = 0; pass < 8; ++pass) {
    float p;
    p  = bflo(ka[pass].x) * qreg[0]  + bfhi(ka[pass].x) * qreg[1];
    p += bflo(ka[pass].y) * qreg[2]  + bfhi(ka[pass].y) * qreg[3];
    p += bflo(ka[pass].z) * qreg[4]  + bfhi(ka[pass].z) * qreg[5];
    p += bflo(ka[pass].w) * qreg[6]  + bfhi(ka[pass].w) * qreg[7];
    p += bflo(kb[pass].x) * qreg[8]  + bfhi(kb[pass].x) * qreg[9];
    p += bflo(kb[pass].y) * qreg[10] + bfhi(kb[pass].y) * qreg[11];
    p += bflo(kb[pass].z) * qreg[12] + bfhi(kb[pass].z) * qreg[13];
    p += bflo(kb[pass].w) * qreg[14] + bfhi(kb[pass].w) * qreg[15];
    p += __shfl_xor(p, 1, 64);
    p += __shfl_xor(p, 2, 64);
    p += __shfl_xor(p, 4, 64);
    float t = __shfl(p, (lane & 7) << 3, 64);
    if (pass == g) mycost = t;
  }
  mycost += qpe * kpe[lane] + rpe[lane];
  // softmax over 64 lanes
  float mx = mycost;
  for (int off = 32; off; off >>= 1) mx = fmaxf(mx, __shfl_xor(mx, off, 64));
  float e = __expf(mycost - mx);
  float ssum = e;
  for (int off = 32; off; off >>= 1) ssum += __shfl_xor(ssum, off, 64);
  float attn = (e / ssum) * mydp;
  float s2 = attn;
  for (int off = 32; off; off >>= 1) s2 += __shfl_xor(s2, off, 64);
  attn = (attn + EPS_R) / (s2 + EPS_R);
  float vpt = attn * vpe[lane];
  for (int off = 32; off; off >>= 1) vpt += __shfl_xor(vpt, off, 64);
  // --- AmV: batches of 8 loads in flight, readlane broadcasts ---
  float o0 = vpt, o1 = vpt;
  unsigned att_u = __float_as_uint(attn);
  #pragma unroll
  for (int blk = 0; blk < 8; ++blk) {
    unsigned vv[8];
    #pragma unroll
    for (int j = 0; j < 8; j++) {
      int row = __builtin_amdgcn_readlane(myidx, blk * 8 + j);
      vv[j] = *(const unsigned*)(Vb + (size_t)row * C + lane * 2);
    }
    #pragma unroll
    for (int j = 0; j < 8; j++) {
      float a = __uint_as_float(__builtin_amdgcn_readlane(att_u, blk * 8 + j));
      o0 += a * bflo(vv[j]);
      o1 += a * bfhi(vv[j]);
    }
  }
  unsigned pk = (unsigned)f2bf(o0) | ((unsigned)f2bf(o1) << 16);
  *(unsigned*)(aoutb + (size_t)token * C + lane * 2) = pk;
}

// ---------------- K4: proj GEMM (MFMA) + residual + fused LayerNorm2 --------------
__global__ __launch_bounds__(256) void k_projln(const unsigned short* __restrict__ aoutb,
    const unsigned short* __restrict__ wt, const float* __restrict__ pb,
    float* __restrict__ xio, const float* __restrict__ g2,
    const float* __restrict__ b2, unsigned short* __restrict__ xn2b) {
  int w = threadIdx.x >> 6, lane = threadIdx.x & 63;
  int q4 = lane >> 4, m = lane & 15;
  int t0 = blockIdx.x * 64 + w * 16;
  const unsigned short* Wt = wt + 3 * 16384;  // pwT
  const unsigned short* ap = aoutb + (size_t)(t0 + m) * C + q4 * 8;
  bf16x8 a[4];
  #pragma unroll
  for (int ks = 0; ks < 4; ks++) a[ks] = *(const bf16x8*)(ap + ks * 32);
  f32x4 acc[8];
  #pragma unroll
  for (int nt = 0; nt < 8; nt++) acc[nt] = (f32x4){0.f, 0.f, 0.f, 0.f};
  #pragma unroll
  for (int nt = 0; nt < 8; nt++) {
    const unsigned short* bp = Wt + (size_t)(nt * 16 + m) * C + q4 * 8;
    #pragma unroll
    for (int ks = 0; ks < 4; ks++) {
      bf16x8 bfrag = *(const bf16x8*)(bp + ks * 32);
      acc[nt] = MFMA16(a[ks], bfrag, acc[nt]);
    }
  }
  float s1[4] = {0.f, 0.f, 0.f, 0.f}, s2[4] = {0.f, 0.f, 0.f, 0.f};
  #pragma unroll
  for (int nt = 0; nt < 8; nt++) {
    int col = nt * 16 + m;
    float bb = pb[col];
    #pragma unroll
    for (int reg = 0; reg < 4; reg++) {
      int row = t0 + q4 * 4 + reg;
      float v = acc[nt][reg] + bb + xio[(size_t)row * C + col];
      acc[nt][reg] = v;
      s1[reg] += v;
      s2[reg] += v * v;
    }
  }
  #pragma unroll
  for (int reg = 0; reg < 4; reg++) {
    #pragma unroll
    for (int off = 1; off < 16; off <<= 1) {
      s1[reg] += __shfl_xor(s1[reg], off, 64);
      s2[reg] += __shfl_xor(s2[reg], off, 64);
    }
  }
  float mean[4], rstd[4];
  #pragma unroll
  for (int reg = 0; reg < 4; reg++) {
    mean[reg] = s1[reg] * (1.0f / 128.0f);
    float var = s2[reg] * (1.0f / 128.0f) - mean[reg] * mean[reg];
    rstd[reg] = rsqrtf(var + LN_EPS);
  }
  #pragma unroll
  for (int nt = 0; nt < 8; nt++) {
    int col = nt * 16 + m;
    float gc = g2[col], bc = b2[col];
    #pragma unroll
    for (int reg = 0; reg < 4; reg++) {
      int row = t0 + q4 * 4 + reg;
      float v = acc[nt][reg];
      xio[(size_t)row * C + col] = v;
      xn2b[(size_t)row * C + col] = f2bf((v - mean[reg]) * rstd[reg] * gc + bc);
    }
  }
}

// ---------------- K5: fc1 GEMM (MFMA) + GELU -> bf16 ------------------------------
__global__ __launch_bounds__(256) void k_fc1(const unsigned short* __restrict__ xn2b,
    const unsigned short* __restrict__ wt, const float* __restrict__ f1b,
    unsigned short* __restrict__ y) {
  int w = threadIdx.x >> 6, lane = threadIdx.x & 63;
  int q4 = lane >> 4, m = lane & 15;
  int t0 = blockIdx.x * 64 + w * 16;
  int n0 = blockIdx.y * 128;
  const unsigned short* Wt = wt + 65536 + (size_t)n0 * C;  // f1wT rows [n0, n0+128)
  const unsigned short* ap = xn2b + (size_t)(t0 + m) * C + q4 * 8;
  bf16x8 a[4];
  #pragma unroll
  for (int ks = 0; ks < 4; ks++) a[ks] = *(const bf16x8*)(ap + ks * 32);
  f32x4 acc[8];
  #pragma unroll
  for (int nt = 0; nt < 8; nt++) acc[nt] = (f32x4){0.f, 0.f, 0.f, 0.f};
  #pragma unroll
  for (int nt = 0; nt < 8; nt++) {
    const unsigned short* bp = Wt + (size_t)(nt * 16 + m) * C + q4 * 8;
    #pragma unroll
    for (int ks = 0; ks < 4; ks++) {
      bf16x8 bfrag = *(const bf16x8*)(bp + ks * 32);
      acc[nt] = MFMA16(a[ks], bfrag, acc[nt]);
    }
  }
  #pragma unroll
  for (int nt = 0; nt < 8; nt++) {
    int col = n0 + nt * 16 + m;
    float bb = f1b[col];
    #pragma unroll
    for (int reg = 0; reg < 4; reg++) {
      int row = t0 + q4 * 4 + reg;
      y[(size_t)row * HID + col] = f2bf(gelu_exact(acc[nt][reg] + bb));
    }
  }
}

// ---------------- K6: depthwise 5x5 conv + GELU (bf16, conflict-free LDS) ---------
__global__ __launch_bounds__(256) void k_dwconv(const unsigned short* __restrict__ y,
    const float* __restrict__ w, const float* __restrict__ bias,
    unsigned short* __restrict__ yc) {
  __shared__ float tile[8][401];   // [channel][spatial 20x20], odd stride
  __shared__ float wl[8][25];
  __shared__ float bl[8];
  int bid = blockIdx.x;
  int tile_id = bid & 15;
  int cb = (bid >> 4) & 31;
  int n = bid >> 9;
  int ty = (tile_id >> 2) * 16, tx = (tile_id & 3) * 16;
  int ch0 = cb * 8;
  int tid = threadIdx.x;
  if (tid < 200) wl[tid / 25][tid % 25] = w[(size_t)(ch0 + tid / 25) * 25 + tid % 25];
  if (tid < 8) bl[tid] = bias[ch0 + tid];
  const unsigned short* yb = y + (size_t)n * HW * HID;
  for (int e = tid; e < 400 * 8; e += 256) {
    int cc = e & 7;
    int p = e >> 3;
    int py = p / 20, px = p % 20;
    int gy = ty + py - 2, gx = tx + px - 2;
    float v = 0.f;
    if (gy >= 0 && gy < 64 && gx >= 0 && gx < 64)
      v = bfu(yb[(size_t)(gy * 64 + gx) * HID + ch0 + cc]);
    tile[cc][p] = v;
  }
  __syncthreads();
  int cc = tid & 7;
  int xx = (tid >> 3) & 15;
  int yg = tid >> 7;
  float wreg[25];
  #pragma unroll
  for (int k = 0; k < 25; k++) wreg[k] = wl[cc][k];
  float bb = bl[cc];
  for (int j = 0; j < 8; ++j) {
    int yy = yg * 8 + j;
    float acc = 0.f;
    #pragma unroll
    for (int dy = 0; dy < 5; ++dy)
      #pragma unroll
      for (int dx = 0; dx < 5; ++dx)
        acc += wreg[dy * 5 + dx] * tile[cc][(yy + dy) * 20 + (xx + dx)];
    acc = gelu_exact(acc + bb);
    yc[(size_t)(n * HW + (ty + yy) * 64 + tx + xx) * HID + ch0 + cc] = f2bf(acc);
  }
}

// ---------------- K7: fc2 GEMM (MFMA) on (y + yc) + final residual -> out ---------
__global__ __launch_bounds__(256) void k_fc2(const unsigned short* __restrict__ y,
    const unsigned short* __restrict__ ycg, const unsigned short* __restrict__ wt,
    const float* __restrict__ f2b, const float* __restrict__ xio,
    float* __restrict__ outp) {
  int w = threadIdx.x >> 6, lane = threadIdx.x & 63;
  int q4 = lane >> 4, m = lane & 15;
  int t0 = blockIdx.x * 64 + w * 16;
  const unsigned short* Wt = wt + 98304;  // f2wT [128][256]
  const unsigned short* ap = y + (size_t)(t0 + m) * HID + q4 * 8;
  const unsigned short* cp = ycg + (size_t)(t0 + m) * HID + q4 * 8;
  union U { bf16x8 v; unsigned short s[8]; };
  bf16x8 a[8];
  #pragma unroll
  for (int ks = 0; ks < 8; ks++) {
    U ua, uc, ur;
    ua.v = *(const bf16x8*)(ap + ks * 32);
    uc.v = *(const bf16x8*)(cp + ks * 32);
    #pragma unroll
    for (int j = 0; j < 8; j++) ur.s[j] = f2bf(bfu(ua.s[j]) + bfu(uc.s[j]));
    a[ks] = ur.v;
  }
  f32x4 acc[8];
  #pragma unroll
  for (int nt = 0; nt < 8; nt++) acc[nt] = (f32x4){0.f, 0.f, 0.f, 0.f};
  #pragma unroll
  for (int nt = 0; nt < 8; nt++) {
    const unsigned short* bp = Wt + (size_t)(nt * 16 + m) * HID + q4 * 8;
    #pragma unroll
    for (int ks = 0; ks < 8; ks++) {
      bf16x8 bfrag = *(const bf16x8*)(bp + ks * 32);
      acc[nt] = MFMA16(a[ks], bfrag, acc[nt]);
    }
  }
  #pragma unroll
  for (int nt = 0; nt < 8; nt++) {
    int col = nt * 16 + m;
    float bb = f2b[col];
    #pragma unroll
    for (int reg = 0; reg < 4; reg++) {
      int row = t0 + q4 * 4 + reg;
      outp[(size_t)row * C + col] = acc[nt][reg] + bb + xio[(size_t)row * C + col];
    }
  }
}

extern "C" void kernel_launch(void* const* d_in, const int* in_sizes, int n_in,
                              void* d_out, int out_size, void* d_ws, size_t ws_size,
                              hipStream_t stream) {
  (void)in_sizes; (void)n_in; (void)out_size; (void)ws_size;
  const float* feat  = (const float*)d_in[0];
  const int*   widx  = (const int*)d_in[1];
  const float* dprob = (const float*)d_in[2];
  const float* ln1g  = (const float*)d_in[3];
  const float* ln1b  = (const float*)d_in[4];
  const float* wq    = (const float*)d_in[5];
  const float* bq    = (const float*)d_in[6];
  const float* wk    = (const float*)d_in[7];
  const float* bk    = (const float*)d_in[8];
  const float* wv    = (const float*)d_in[9];
  const float* bv    = (const float*)d_in[10];
  const float* kpe   = (const float*)d_in[11];
  const float* vpe   = (const float*)d_in[12];
  const float* rpe   = (const float*)d_in[13];
  const float* pw    = (const float*)d_in[14];
  const float* pb    = (const float*)d_in[15];
  const float* ln2g  = (const float*)d_in[16];
  const float* ln2b  = (const float*)d_in[17];
  const float* f1w   = (const float*)d_in[18];
  const float* f1b   = (const float*)d_in[19];
  const float* dww   = (const float*)d_in[20];
  const float* dwb   = (const float*)d_in[21];
  const float* f2w   = (const float*)d_in[22];
  const float* f2b   = (const float*)d_in[23];

  float* ws = (float*)d_ws;
  const size_t M2 = (size_t)TOK * C;  // 2,097,152 floats (8 MB)
  float* qb  = ws;                                                   // fp32 q (scaled)
  float* xio = ws + M2;                                              // fp32 residual stream
  unsigned short* xnb   = (unsigned short*)(ws + 2 * M2);            // bf16 ln1 out
  unsigned short* ksb   = (unsigned short*)(ws + 2 * M2 + M2 / 2);   // bf16 K (swapped)
  unsigned short* vsb   = (unsigned short*)(ws + 3 * M2);            // bf16 V (swapped)
  unsigned short* aoutb = (unsigned short*)(ws + 3 * M2 + M2 / 2);   // bf16 attn out
  unsigned short* xn2b  = (unsigned short*)(ws + 4 * M2);            // bf16 ln2 out
  unsigned short* yb    = (unsigned short*)(ws + 4 * M2 + M2 / 2);   // bf16 fc1 out (2*M2 ush)
  unsigned short* ycgb  = (unsigned short*)(ws + 5 * M2 + M2 / 2);   // bf16 dwconv out (2*M2 ush)
  unsigned short* wtb   = (unsigned short*)(ws + 6 * M2 + M2 / 2);   // bf16 weights (131072 ush)

  k_prep  <<<512, 256, 0, stream>>>(wq, wk, wv, pw, f1w, f2w, wtb);
  k_ln1   <<<TOK / 64, 256, 0, stream>>>(feat, ln1g, ln1b, xnb, xio);
  k_qkv   <<<dim3(TOK / 64, 3), 256, 0, stream>>>(xnb, wtb, bq, bk, bv, qb, ksb, vsb);
  k_attn  <<<TOK / 4, 256, 0, stream>>>(qb, ksb, vsb, widx, dprob, kpe, vpe, rpe, aoutb);
  k_projln<<<TOK / 64, 256, 0, stream>>>(aoutb, wtb, pb, xio, ln2g, ln2b, xn2b);
  k_fc1   <<<dim3(TOK / 64, 2), 256, 0, stream>>>(xn2b, wtb, f1b, yb);
  k_dwconv<<<2048, 256, 0, stream>>>(yb, dww, dwb, ycgb);
  k_fc2   <<<TOK / 64, 256, 0, stream>>>(yb, ycgb, wtb, f2b, xio, (float*)d_out);
}

// Round 7
// 216.494 us; speedup vs baseline: 1.0686x; 1.0038x over previous
//
#include <hip/hip_runtime.h>
#include <math.h>

#define TOK   16384   // Bf * hw
#define HW    4096
#define C     128
#define D     64
#define HID   256

constexpr float LN_EPS = 1e-5f;
constexpr float EPS_R  = 1e-10f;
constexpr float QSCALE = 0.08838834764831845f; // 128^-0.5

typedef __attribute__((ext_vector_type(8))) short  bf16x8;
typedef __attribute__((ext_vector_type(4))) float  f32x4;
#define MFMA16(a, b, c) __builtin_amdgcn_mfma_f32_16x16x32_bf16((a), (b), (c), 0, 0, 0)

__device__ __forceinline__ float bflo(unsigned u) { return __uint_as_float(u << 16); }
__device__ __forceinline__ float bfhi(unsigned u) { return __uint_as_float(u & 0xffff0000u); }
__device__ __forceinline__ float bfu(unsigned short u) { return __uint_as_float((unsigned)u << 16); }
__device__ __forceinline__ unsigned short f2bf(float f) {
  unsigned u = __float_as_uint(f);
  unsigned r = (u + 0x7fffu + ((u >> 16) & 1u)) >> 16;
  return (unsigned short)r;
}
__device__ __forceinline__ float gelu_exact(float x) {
  return 0.5f * x * (1.0f + erff(x * 0.7071067811865476f));
}

// ---------------- K0: weight prep -> bf16, transposed Wt[n][k] --------------------
__global__ __launch_bounds__(256) void k_prep(const float* __restrict__ wq,
    const float* __restrict__ wk, const float* __restrict__ wv,
    const float* __restrict__ pw, const float* __restrict__ f1w,
    const float* __restrict__ f2w, unsigned short* __restrict__ wt) {
  int id = blockIdx.x * 256 + threadIdx.x;
  if (id < 16384) {
    int n = id >> 7, k = id & 127;
    wt[id] = f2bf(wq[k * 128 + n]);
  } else if (id < 32768) {
    int e = id - 16384; int n = e >> 7, k = e & 127;
    wt[id] = f2bf(wk[k * 128 + n]);
  } else if (id < 49152) {
    int e = id - 32768; int n = e >> 7, k = e & 127;
    wt[id] = f2bf(wv[k * 128 + n]);
  } else if (id < 65536) {
    int e = id - 49152; int n = e >> 7, k = e & 127;
    wt[id] = f2bf(pw[k * 128 + n]);
  } else if (id < 98304) {
    int e = id - 65536; int n = e >> 7, k = e & 127;   // n in [0,256), k in [0,128)
    wt[id] = f2bf(f1w[k * 256 + n]);
  } else if (id < 131072) {
    int e = id - 98304; int n = e >> 8, k = e & 255;   // n in [0,128), k in [0,256)
    wt[id] = f2bf(f2w[k * 128 + n]);
  }
}

// ---------------- K1: transpose (NCHW -> token-major) + LayerNorm1 -> bf16 --------
__global__ __launch_bounds__(256) void k_ln1(const float* __restrict__ feat,
    const float* __restrict__ g, const float* __restrict__ b,
    unsigned short* __restrict__ xnb) {
  __shared__ float tile[64][C + 1];
  int t0 = blockIdx.x * 64;
  int n = t0 / HW, i0 = t0 % HW;
  int tid = threadIdx.x;
  const float* fb = feat + (size_t)n * C * HW;
  for (int e = tid; e < 64 * C; e += 256) {
    int ch = e >> 6, ii = e & 63;
    tile[ii][ch] = fb[(size_t)ch * HW + i0 + ii];
  }
  __syncthreads();
  int wave = tid >> 6, lane = tid & 63;
  for (int tkn = wave; tkn < 64; tkn += 4) {
    float a0 = tile[tkn][lane];
    float a1 = tile[tkn][lane + 64];
    float s = a0 + a1;
    for (int off = 32; off; off >>= 1) s += __shfl_xor(s, off, 64);
    float mean = s * (1.0f / 128.0f);
    float d0 = a0 - mean, d1 = a1 - mean;
    float v = d0 * d0 + d1 * d1;
    for (int off = 32; off; off >>= 1) v += __shfl_xor(v, off, 64);
    float rstd = rsqrtf(v * (1.0f / 128.0f) + LN_EPS);
    size_t ro = (size_t)(t0 + tkn) * C;
    xnb[ro + lane]      = f2bf(d0 * rstd * g[lane] + b[lane]);
    xnb[ro + lane + 64] = f2bf(d1 * rstd * g[lane + 64] + b[lane + 64]);
  }
}

// ---------------- K2: QKV GEMM via MFMA (blockIdx.y selects q/k/v; all bf16 out) --
__global__ __launch_bounds__(256) void k_qkv(const unsigned short* __restrict__ xnb,
    const unsigned short* __restrict__ wt,
    const float* __restrict__ bq, const float* __restrict__ bk,
    const float* __restrict__ bv, unsigned short* __restrict__ qb,
    unsigned short* __restrict__ ksw, unsigned short* __restrict__ vsw) {
  int w = threadIdx.x >> 6, lane = threadIdx.x & 63;
  int q4 = lane >> 4, m = lane & 15;
  int t0 = blockIdx.x * 64 + w * 16;
  int wsel = blockIdx.y;
  const unsigned short* Wt = wt + wsel * 16384;
  const unsigned short* ap = xnb + (size_t)(t0 + m) * C + q4 * 8;
  bf16x8 a[4];
  #pragma unroll
  for (int ks = 0; ks < 4; ks++) a[ks] = *(const bf16x8*)(ap + ks * 32);
  f32x4 acc[8];
  #pragma unroll
  for (int nt = 0; nt < 8; nt++) acc[nt] = (f32x4){0.f, 0.f, 0.f, 0.f};
  #pragma unroll
  for (int nt = 0; nt < 8; nt++) {
    const unsigned short* bp = Wt + (size_t)(nt * 16 + m) * C + q4 * 8;
    #pragma unroll
    for (int ks = 0; ks < 4; ks++) {
      bf16x8 bfrag = *(const bf16x8*)(bp + ks * 32);
      acc[nt] = MFMA16(a[ks], bfrag, acc[nt]);
    }
  }
  const float* B = (wsel == 0) ? bq : ((wsel == 1) ? bk : bv);
  float sc = (wsel == 0) ? QSCALE : 1.0f;
  unsigned short* O = (wsel == 0) ? qb : ((wsel == 1) ? ksw : vsw);
  int n = t0 >> 12, i0 = t0 & 4095;
  int base = (wsel == 0) ? t0 : (((n ^ 1) << 12) + i0);
  #pragma unroll
  for (int nt = 0; nt < 8; nt++) {
    int col = nt * 16 + m;
    float bb = B[col];
    #pragma unroll
    for (int reg = 0; reg < 4; reg++) {
      int row = base + q4 * 4 + reg;
      O[(size_t)row * C + col] = f2bf((acc[nt][reg] + bb) * sc);
    }
  }
}

// ---------------- K3: gather attention (hoisted loads, readlane, XCD swizzle) -----
__global__ __launch_bounds__(256) void k_attn(const unsigned short* __restrict__ qb,
    const unsigned short* __restrict__ ksw, const unsigned short* __restrict__ vsw,
    const int* __restrict__ widx, const float* __restrict__ dprob,
    const float* __restrict__ kpe, const float* __restrict__ vpe,
    const float* __restrict__ rpe, unsigned short* __restrict__ aoutb) {
  int lane = threadIdx.x & 63;
  int wave = threadIdx.x >> 6;
  int bid = blockIdx.x;
  int n = (bid >> 1) & 3;
  int within = ((bid >> 3) << 1) | (bid & 1);
  int token = n * HW + within * 4 + wave;
  const unsigned short* Kb = ksw + (size_t)n * HW * C;
  const unsigned short* Vb = vsw + (size_t)n * HW * C;
  int g = lane >> 3, s = lane & 7;
  int myidx = widx[token * D + lane];
  float mydp = dprob[token * D + lane];
  // Q segment (bf16): channels [s*16, s*16+16)
  float qreg[16];
  {
    const unsigned short* qp = qb + (size_t)token * C + s * 16;
    uint4 qa = *(const uint4*)(qp);
    uint4 qbv = *(const uint4*)(qp + 8);
    qreg[0] = bflo(qa.x);  qreg[1] = bfhi(qa.x);
    qreg[2] = bflo(qa.y);  qreg[3] = bfhi(qa.y);
    qreg[4] = bflo(qa.z);  qreg[5] = bfhi(qa.z);
    qreg[6] = bflo(qa.w);  qreg[7] = bfhi(qa.w);
    qreg[8] = bflo(qbv.x); qreg[9] = bfhi(qbv.x);
    qreg[10] = bflo(qbv.y); qreg[11] = bfhi(qbv.y);
    qreg[12] = bflo(qbv.z); qreg[13] = bfhi(qbv.z);
    qreg[14] = bflo(qbv.w); qreg[15] = bfhi(qbv.w);
  }
  float qpe = 0.f;
  #pragma unroll
  for (int i = 0; i < 16; i++) qpe += qreg[i];
  qpe += __shfl_xor(qpe, 1, 64);
  qpe += __shfl_xor(qpe, 2, 64);
  qpe += __shfl_xor(qpe, 4, 64);
  // QmK: hoist 8 row indices, then all 16 loads (MLP), then compute
  int rowv[8];
  #pragma unroll
  for (int pass = 0; pass < 8; ++pass)
    rowv[pass] = __shfl(myidx, pass * 8 + g, 64);
  uint4 ka[8], kb[8];
  #pragma unroll
  for (int pass = 0; pass < 8; ++pass) {
    const unsigned short* kr = Kb + (size_t)rowv[pass] * C + s * 16;
    ka[pass] = *(const uint4*)(kr);
    kb[pass] = *(const uint4*)(kr + 8);
  }
  float mycost = 0.f;
  #pragma unroll
  for (int pass = 0; pass < 8; ++pass) {
    float p;
    p  = bflo(ka[pass].x) * qreg[0]  + bfhi(ka[pass].x) * qreg[1];
    p += bflo(ka[pass].y) * qreg[2]  + bfhi(ka[pass].y) * qreg[3];
    p += bflo(ka[pass].z) * qreg[4]  + bfhi(ka[pass].z) * qreg[5];
    p += bflo(ka[pass].w) * qreg[6]  + bfhi(ka[pass].w) * qreg[7];
    p += bflo(kb[pass].x) * qreg[8]  + bfhi(kb[pass].x) * qreg[9];
    p += bflo(kb[pass].y) * qreg[10] + bfhi(kb[pass].y) * qreg[11];
    p += bflo(kb[pass].z) * qreg[12] + bfhi(kb[pass].z) * qreg[13];
    p += bflo(kb[pass].w) * qreg[14] + bfhi(kb[pass].w) * qreg[15];
    p += __shfl_xor(p, 1, 64);
    p += __shfl_xor(p, 2, 64);
    p += __shfl_xor(p, 4, 64);
    float t = __shfl(p, (lane & 7) << 3, 64);
    if (pass == g) mycost = t;
  }
  mycost += qpe * kpe[lane] + rpe[lane];
  float mx = mycost;
  for (int off = 32; off; off >>= 1) mx = fmaxf(mx, __shfl_xor(mx, off, 64));
  float e = __expf(mycost - mx);
  float ssum = e;
  for (int off = 32; off; off >>= 1) ssum += __shfl_xor(ssum, off, 64);
  float attn = (e / ssum) * mydp;
  float s2 = attn;
  for (int off = 32; off; off >>= 1) s2 += __shfl_xor(s2, off, 64);
  attn = (attn + EPS_R) / (s2 + EPS_R);
  float vpt = attn * vpe[lane];
  for (int off = 32; off; off >>= 1) vpt += __shfl_xor(vpt, off, 64);
  // AmV: batches of 8 loads in flight, readlane broadcasts
  float o0 = vpt, o1 = vpt;
  unsigned att_u = __float_as_uint(attn);
  #pragma unroll
  for (int blk = 0; blk < 8; ++blk) {
    unsigned vv[8];
    #pragma unroll
    for (int j = 0; j < 8; j++) {
      int row = __builtin_amdgcn_readlane(myidx, blk * 8 + j);
      vv[j] = *(const unsigned*)(Vb + (size_t)row * C + lane * 2);
    }
    #pragma unroll
    for (int j = 0; j < 8; j++) {
      float a = __uint_as_float(__builtin_amdgcn_readlane(att_u, blk * 8 + j));
      o0 += a * bflo(vv[j]);
      o1 += a * bfhi(vv[j]);
    }
  }
  unsigned pk = (unsigned)f2bf(o0) | ((unsigned)f2bf(o1) << 16);
  *(unsigned*)(aoutb + (size_t)token * C + lane * 2) = pk;
}

// ---------------- K4: proj GEMM + residual(from feat, transposed) + LN2 -----------
__global__ __launch_bounds__(256) void k_projln(const unsigned short* __restrict__ aoutb,
    const unsigned short* __restrict__ wt, const float* __restrict__ pb,
    const float* __restrict__ feat, float* __restrict__ xio,
    const float* __restrict__ g2, const float* __restrict__ b2,
    unsigned short* __restrict__ xn2b) {
  int w = threadIdx.x >> 6, lane = threadIdx.x & 63;
  int q4 = lane >> 4, m = lane & 15;
  int t0 = blockIdx.x * 64 + w * 16;
  const unsigned short* Wt = wt + 3 * 16384;  // pwT
  const unsigned short* ap = aoutb + (size_t)(t0 + m) * C + q4 * 8;
  bf16x8 a[4];
  #pragma unroll
  for (int ks = 0; ks < 4; ks++) a[ks] = *(const bf16x8*)(ap + ks * 32);
  f32x4 acc[8];
  #pragma unroll
  for (int nt = 0; nt < 8; nt++) acc[nt] = (f32x4){0.f, 0.f, 0.f, 0.f};
  #pragma unroll
  for (int nt = 0; nt < 8; nt++) {
    const unsigned short* bp = Wt + (size_t)(nt * 16 + m) * C + q4 * 8;
    #pragma unroll
    for (int ks = 0; ks < 4; ks++) {
      bf16x8 bfrag = *(const bf16x8*)(bp + ks * 32);
      acc[nt] = MFMA16(a[ks], bfrag, acc[nt]);
    }
  }
  // residual from original features (transposed read): feat[n][col][i]
  int nview = t0 >> 12, ibase = (t0 & 4095) + q4 * 4;
  float s1[4] = {0.f, 0.f, 0.f, 0.f}, s2[4] = {0.f, 0.f, 0.f, 0.f};
  #pragma unroll
  for (int nt = 0; nt < 8; nt++) {
    int col = nt * 16 + m;
    float bb = pb[col];
    const float* fp = feat + ((size_t)nview * C + col) * HW + ibase;
    #pragma unroll
    for (int reg = 0; reg < 4; reg++) {
      float v = acc[nt][reg] + bb + fp[reg];
      acc[nt][reg] = v;
      s1[reg] += v;
      s2[reg] += v * v;
    }
  }
  #pragma unroll
  for (int reg = 0; reg < 4; reg++) {
    #pragma unroll
    for (int off = 1; off < 16; off <<= 1) {
      s1[reg] += __shfl_xor(s1[reg], off, 64);
      s2[reg] += __shfl_xor(s2[reg], off, 64);
    }
  }
  float mean[4], rstd[4];
  #pragma unroll
  for (int reg = 0; reg < 4; reg++) {
    mean[reg] = s1[reg] * (1.0f / 128.0f);
    float var = s2[reg] * (1.0f / 128.0f) - mean[reg] * mean[reg];
    rstd[reg] = rsqrtf(var + LN_EPS);
  }
  #pragma unroll
  for (int nt = 0; nt < 8; nt++) {
    int col = nt * 16 + m;
    float gc = g2[col], bc = b2[col];
    #pragma unroll
    for (int reg = 0; reg < 4; reg++) {
      int row = t0 + q4 * 4 + reg;
      float v = acc[nt][reg];
      xio[(size_t)row * C + col] = v;
      xn2b[(size_t)row * C + col] = f2bf((v - mean[reg]) * rstd[reg] * gc + bc);
    }
  }
}

// ---------------- K5: fc1 GEMM (MFMA, y-split x2) + GELU -> bf16 ------------------
__global__ __launch_bounds__(256) void k_fc1(const unsigned short* __restrict__ xn2b,
    const unsigned short* __restrict__ wt, const float* __restrict__ f1b,
    unsigned short* __restrict__ y) {
  int w = threadIdx.x >> 6, lane = threadIdx.x & 63;
  int q4 = lane >> 4, m = lane & 15;
  int t0 = blockIdx.x * 64 + w * 16;
  int n0 = blockIdx.y * 128;
  const unsigned short* Wt = wt + 65536 + (size_t)n0 * C;  // f1wT rows [n0, n0+128)
  const unsigned short* ap = xn2b + (size_t)(t0 + m) * C + q4 * 8;
  bf16x8 a[4];
  #pragma unroll
  for (int ks = 0; ks < 4; ks++) a[ks] = *(const bf16x8*)(ap + ks * 32);
  f32x4 acc[8];
  #pragma unroll
  for (int nt = 0; nt < 8; nt++) acc[nt] = (f32x4){0.f, 0.f, 0.f, 0.f};
  #pragma unroll
  for (int nt = 0; nt < 8; nt++) {
    const unsigned short* bp = Wt + (size_t)(nt * 16 + m) * C + q4 * 8;
    #pragma unroll
    for (int ks = 0; ks < 4; ks++) {
      bf16x8 bfrag = *(const bf16x8*)(bp + ks * 32);
      acc[nt] = MFMA16(a[ks], bfrag, acc[nt]);
    }
  }
  #pragma unroll
  for (int nt = 0; nt < 8; nt++) {
    int col = n0 + nt * 16 + m;
    float bb = f1b[col];
    #pragma unroll
    for (int reg = 0; reg < 4; reg++) {
      int row = t0 + q4 * 4 + reg;
      y[(size_t)row * HID + col] = f2bf(gelu_exact(acc[nt][reg] + bb));
    }
  }
}

// ---------------- K6: depthwise 5x5 conv + GELU (register window) -----------------
__global__ __launch_bounds__(256) void k_dwconv(const unsigned short* __restrict__ y,
    const float* __restrict__ w, const float* __restrict__ bias,
    unsigned short* __restrict__ yc) {
  __shared__ float tile[8][401];   // [channel][spatial 20x20], odd stride
  __shared__ float wl[8][25];
  __shared__ float bl[8];
  int bid = blockIdx.x;
  int tile_id = bid & 15;
  int cb = (bid >> 4) & 31;
  int n = bid >> 9;
  int ty = (tile_id >> 2) * 16, tx = (tile_id & 3) * 16;
  int ch0 = cb * 8;
  int tid = threadIdx.x;
  if (tid < 200) wl[tid / 25][tid % 25] = w[(size_t)(ch0 + tid / 25) * 25 + tid % 25];
  if (tid < 8) bl[tid] = bias[ch0 + tid];
  const unsigned short* yb = y + (size_t)n * HW * HID;
  for (int e = tid; e < 400 * 8; e += 256) {
    int cc = e & 7;
    int p = e >> 3;
    int py = p / 20, px = p % 20;
    int gy = ty + py - 2, gx = tx + px - 2;
    float v = 0.f;
    if (gy >= 0 && gy < 64 && gx >= 0 && gx < 64)
      v = bfu(yb[(size_t)(gy * 64 + gx) * HID + ch0 + cc]);
    tile[cc][p] = v;
  }
  __syncthreads();
  int cc = tid & 7;
  int xx = (tid >> 3) & 15;
  int yg = tid >> 7;
  float wreg[25];
  #pragma unroll
  for (int k = 0; k < 25; k++) wreg[k] = wl[cc][k];
  float bb = bl[cc];
  // load the 12x5 input window into registers (60 LDS reads instead of 200)
  float win[12][5];
  #pragma unroll
  for (int r = 0; r < 12; r++)
    #pragma unroll
    for (int dx = 0; dx < 5; dx++)
      win[r][dx] = tile[cc][(yg * 8 + r) * 20 + xx + dx];
  #pragma unroll
  for (int j = 0; j < 8; ++j) {
    float acc = 0.f;
    #pragma unroll
    for (int dy = 0; dy < 5; ++dy)
      #pragma unroll
      for (int dx = 0; dx < 5; ++dx)
        acc += wreg[dy * 5 + dx] * win[j + dy][dx];
    acc = gelu_exact(acc + bb);
    int yy = yg * 8 + j;
    yc[(size_t)(n * HW + (ty + yy) * 64 + tx + xx) * HID + ch0 + cc] = f2bf(acc);
  }
}

// ---------------- K7: fc2 GEMM (MFMA, col-split x2) on (y+yc) + residual ----------
__global__ __launch_bounds__(256) void k_fc2(const unsigned short* __restrict__ y,
    const unsigned short* __restrict__ ycg, const unsigned short* __restrict__ wt,
    const float* __restrict__ f2b, const float* __restrict__ xio,
    float* __restrict__ outp) {
  int w = threadIdx.x >> 6, lane = threadIdx.x & 63;
  int q4 = lane >> 4, m = lane & 15;
  int t0 = blockIdx.x * 64 + w * 16;
  int half = blockIdx.y;
  const unsigned short* Wt = wt + 98304;  // f2wT [128][256]
  const unsigned short* ap = y + (size_t)(t0 + m) * HID + q4 * 8;
  const unsigned short* cp = ycg + (size_t)(t0 + m) * HID + q4 * 8;
  union U { bf16x8 v; unsigned short s[8]; };
  bf16x8 a[8];
  #pragma unroll
  for (int ks = 0; ks < 8; ks++) {
    U ua, uc, ur;
    ua.v = *(const bf16x8*)(ap + ks * 32);
    uc.v = *(const bf16x8*)(cp + ks * 32);
    #pragma unroll
    for (int j = 0; j < 8; j++) ur.s[j] = f2bf(bfu(ua.s[j]) + bfu(uc.s[j]));
    a[ks] = ur.v;
  }
  f32x4 acc[4];
  #pragma unroll
  for (int nt = 0; nt < 4; nt++) acc[nt] = (f32x4){0.f, 0.f, 0.f, 0.f};
  #pragma unroll
  for (int nt = 0; nt < 4; nt++) {
    const unsigned short* bp = Wt + (size_t)(half * 64 + nt * 16 + m) * HID + q4 * 8;
    #pragma unroll
    for (int ks = 0; ks < 8; ks++) {
      bf16x8 bfrag = *(const bf16x8*)(bp + ks * 32);
      acc[nt] = MFMA16(a[ks], bfrag, acc[nt]);
    }
  }
  #pragma unroll
  for (int nt = 0; nt < 4; nt++) {
    int col = half * 64 + nt * 16 + m;
    float bb = f2b[col];
    #pragma unroll
    for (int reg = 0; reg < 4; reg++) {
      int row = t0 + q4 * 4 + reg;
      outp[(size_t)row * C + col] = acc[nt][reg] + bb + xio[(size_t)row * C + col];
    }
  }
}

extern "C" void kernel_launch(void* const* d_in, const int* in_sizes, int n_in,
                              void* d_out, int out_size, void* d_ws, size_t ws_size,
                              hipStream_t stream) {
  (void)in_sizes; (void)n_in; (void)out_size; (void)ws_size;
  const float* feat  = (const float*)d_in[0];
  const int*   widx  = (const int*)d_in[1];
  const float* dprob = (const float*)d_in[2];
  const float* ln1g  = (const float*)d_in[3];
  const float* ln1b  = (const float*)d_in[4];
  const float* wq    = (const float*)d_in[5];
  const float* bq    = (const float*)d_in[6];
  const float* wk    = (const float*)d_in[7];
  const float* bk    = (const float*)d_in[8];
  const float* wv    = (const float*)d_in[9];
  const float* bv    = (const float*)d_in[10];
  const float* kpe   = (const float*)d_in[11];
  const float* vpe   = (const float*)d_in[12];
  const float* rpe   = (const float*)d_in[13];
  const float* pw    = (const float*)d_in[14];
  const float* pb    = (const float*)d_in[15];
  const float* ln2g  = (const float*)d_in[16];
  const float* ln2b  = (const float*)d_in[17];
  const float* f1w   = (const float*)d_in[18];
  const float* f1b   = (const float*)d_in[19];
  const float* dww   = (const float*)d_in[20];
  const float* dwb   = (const float*)d_in[21];
  const float* f2w   = (const float*)d_in[22];
  const float* f2b   = (const float*)d_in[23];

  float* ws = (float*)d_ws;
  const size_t M2 = (size_t)TOK * C;  // 2,097,152 floats (8 MB)
  float* xio = ws;                                                   // fp32 residual stream
  unsigned short* qbb   = (unsigned short*)(ws + M2);                // bf16 q (scaled)
  unsigned short* xnb   = (unsigned short*)(ws + M2 + M2 / 2);       // bf16 ln1 out
  unsigned short* ksb   = (unsigned short*)(ws + 2 * M2);            // bf16 K (swapped)
  unsigned short* vsb   = (unsigned short*)(ws + 2 * M2 + M2 / 2);   // bf16 V (swapped)
  unsigned short* aoutb = (unsigned short*)(ws + 3 * M2);            // bf16 attn out
  unsigned short* xn2b  = (unsigned short*)(ws + 3 * M2 + M2 / 2);   // bf16 ln2 out
  unsigned short* yb    = (unsigned short*)(ws + 4 * M2);            // bf16 fc1 out (2*M2 ush)
  unsigned short* ycgb  = (unsigned short*)(ws + 5 * M2);            // bf16 dwconv out (2*M2 ush)
  unsigned short* wtb   = (unsigned short*)(ws + 6 * M2);            // bf16 weights (131072 ush)

  k_prep  <<<512, 256, 0, stream>>>(wq, wk, wv, pw, f1w, f2w, wtb);
  k_ln1   <<<TOK / 64, 256, 0, stream>>>(feat, ln1g, ln1b, xnb);
  k_qkv   <<<dim3(TOK / 64, 3), 256, 0, stream>>>(xnb, wtb, bq, bk, bv, qbb, ksb, vsb);
  k_attn  <<<TOK / 4, 256, 0, stream>>>(qbb, ksb, vsb, widx, dprob, kpe, vpe, rpe, aoutb);
  k_projln<<<TOK / 64, 256, 0, stream>>>(aoutb, wtb, pb, feat, xio, ln2g, ln2b, xn2b);
  k_fc1   <<<dim3(TOK / 64, 2), 256, 0, stream>>>(xn2b, wtb, f1b, yb);
  k_dwconv<<<2048, 256, 0, stream>>>(yb, dww, dwb, ycgb);
  k_fc2   <<<dim3(TOK / 64, 2), 256, 0, stream>>>(yb, ycgb, wtb, f2b, xio, (float*)d_out);
}

// Round 8
// 210.954 us; speedup vs baseline: 1.0967x; 1.0263x over previous
//
#include <hip/hip_runtime.h>
#include <math.h>

#define TOK   16384   // Bf * hw
#define HW    4096
#define C     128
#define D     64
#define HID   256

constexpr float LN_EPS = 1e-5f;
constexpr float EPS_R  = 1e-10f;
constexpr float QSCALE = 0.08838834764831845f; // 128^-0.5

typedef __attribute__((ext_vector_type(8))) short  bf16x8;
typedef __attribute__((ext_vector_type(4))) float  f32x4;
typedef __attribute__((ext_vector_type(2))) _Float16 half2v;
#define MFMA16(a, b, c) __builtin_amdgcn_mfma_f32_16x16x32_bf16((a), (b), (c), 0, 0, 0)

__device__ __forceinline__ float bflo(unsigned u) { return __uint_as_float(u << 16); }
__device__ __forceinline__ float bfhi(unsigned u) { return __uint_as_float(u & 0xffff0000u); }
__device__ __forceinline__ float bfu(unsigned short u) { return __uint_as_float((unsigned)u << 16); }
__device__ __forceinline__ unsigned short f2bf(float f) {
  unsigned u = __float_as_uint(f);
  unsigned r = (u + 0x7fffu + ((u >> 16) & 1u)) >> 16;
  return (unsigned short)r;
}
__device__ __forceinline__ unsigned short f2h(float f) {
  _Float16 h = (_Float16)f;
  unsigned short r;
  __builtin_memcpy(&r, &h, 2);
  return r;
}
__device__ __forceinline__ float gelu_exact(float x) {
  return 0.5f * x * (1.0f + erff(x * 0.7071067811865476f));
}

union U4H { uint4 v; half2v h[4]; };

#if __has_builtin(__builtin_amdgcn_fdot2)
__device__ __forceinline__ float dot2h(half2v a, half2v b, float c) {
  return __builtin_amdgcn_fdot2(a, b, c, false);
}
#else
__device__ __forceinline__ float dot2h(half2v a, half2v b, float c) {
  return c + (float)a.x * (float)b.x + (float)a.y * (float)b.y;
}
#endif

// ---------------- K0: weight prep -> bf16, transposed Wt[n][k] --------------------
__global__ __launch_bounds__(256) void k_prep(const float* __restrict__ wq,
    const float* __restrict__ wk, const float* __restrict__ wv,
    const float* __restrict__ pw, const float* __restrict__ f1w,
    const float* __restrict__ f2w, unsigned short* __restrict__ wt) {
  int id = blockIdx.x * 256 + threadIdx.x;
  if (id < 16384) {
    int n = id >> 7, k = id & 127;
    wt[id] = f2bf(wq[k * 128 + n]);
  } else if (id < 32768) {
    int e = id - 16384; int n = e >> 7, k = e & 127;
    wt[id] = f2bf(wk[k * 128 + n]);
  } else if (id < 49152) {
    int e = id - 32768; int n = e >> 7, k = e & 127;
    wt[id] = f2bf(wv[k * 128 + n]);
  } else if (id < 65536) {
    int e = id - 49152; int n = e >> 7, k = e & 127;
    wt[id] = f2bf(pw[k * 128 + n]);
  } else if (id < 98304) {
    int e = id - 65536; int n = e >> 7, k = e & 127;   // n in [0,256), k in [0,128)
    wt[id] = f2bf(f1w[k * 256 + n]);
  } else if (id < 131072) {
    int e = id - 98304; int n = e >> 8, k = e & 255;   // n in [0,128), k in [0,256)
    wt[id] = f2bf(f2w[k * 128 + n]);
  }
}

// ---------------- K1: transpose (NCHW -> token-major) + LayerNorm1 -> bf16 --------
__global__ __launch_bounds__(256) void k_ln1(const float* __restrict__ feat,
    const float* __restrict__ g, const float* __restrict__ b,
    unsigned short* __restrict__ xnb) {
  __shared__ float tile[64][C + 1];
  int t0 = blockIdx.x * 64;
  int n = t0 / HW, i0 = t0 % HW;
  int tid = threadIdx.x;
  const float* fb = feat + (size_t)n * C * HW;
  for (int e = tid; e < 64 * C; e += 256) {
    int ch = e >> 6, ii = e & 63;
    tile[ii][ch] = fb[(size_t)ch * HW + i0 + ii];
  }
  __syncthreads();
  int wave = tid >> 6, lane = tid & 63;
  for (int tkn = wave; tkn < 64; tkn += 4) {
    float a0 = tile[tkn][lane];
    float a1 = tile[tkn][lane + 64];
    float s = a0 + a1;
    for (int off = 32; off; off >>= 1) s += __shfl_xor(s, off, 64);
    float mean = s * (1.0f / 128.0f);
    float d0 = a0 - mean, d1 = a1 - mean;
    float v = d0 * d0 + d1 * d1;
    for (int off = 32; off; off >>= 1) v += __shfl_xor(v, off, 64);
    float rstd = rsqrtf(v * (1.0f / 128.0f) + LN_EPS);
    size_t ro = (size_t)(t0 + tkn) * C;
    xnb[ro + lane]      = f2bf(d0 * rstd * g[lane] + b[lane]);
    xnb[ro + lane + 64] = f2bf(d1 * rstd * g[lane + 64] + b[lane + 64]);
  }
}

// ---------------- K2: QKV GEMM via MFMA; Q,K out fp16; V out bf16 -----------------
__global__ __launch_bounds__(256) void k_qkv(const unsigned short* __restrict__ xnb,
    const unsigned short* __restrict__ wt,
    const float* __restrict__ bq, const float* __restrict__ bk,
    const float* __restrict__ bv, unsigned short* __restrict__ qh,
    unsigned short* __restrict__ ksw, unsigned short* __restrict__ vsw) {
  int w = threadIdx.x >> 6, lane = threadIdx.x & 63;
  int q4 = lane >> 4, m = lane & 15;
  int t0 = blockIdx.x * 64 + w * 16;
  int wsel = blockIdx.y;
  const unsigned short* Wt = wt + wsel * 16384;
  const unsigned short* ap = xnb + (size_t)(t0 + m) * C + q4 * 8;
  bf16x8 a[4];
  #pragma unroll
  for (int ks = 0; ks < 4; ks++) a[ks] = *(const bf16x8*)(ap + ks * 32);
  f32x4 acc[8];
  #pragma unroll
  for (int nt = 0; nt < 8; nt++) acc[nt] = (f32x4){0.f, 0.f, 0.f, 0.f};
  #pragma unroll
  for (int nt = 0; nt < 8; nt++) {
    const unsigned short* bp = Wt + (size_t)(nt * 16 + m) * C + q4 * 8;
    #pragma unroll
    for (int ks = 0; ks < 4; ks++) {
      bf16x8 bfrag = *(const bf16x8*)(bp + ks * 32);
      acc[nt] = MFMA16(a[ks], bfrag, acc[nt]);
    }
  }
  const float* B = (wsel == 0) ? bq : ((wsel == 1) ? bk : bv);
  float sc = (wsel == 0) ? QSCALE : 1.0f;
  unsigned short* O = (wsel == 0) ? qh : ((wsel == 1) ? ksw : vsw);
  int n = t0 >> 12, i0 = t0 & 4095;
  int base = (wsel == 0) ? t0 : (((n ^ 1) << 12) + i0);
  #pragma unroll
  for (int nt = 0; nt < 8; nt++) {
    int col = nt * 16 + m;
    float bb = B[col];
    #pragma unroll
    for (int reg = 0; reg < 4; reg++) {
      int row = base + q4 * 4 + reg;
      float v = (acc[nt][reg] + bb) * sc;
      O[(size_t)row * C + col] = (wsel == 2) ? f2bf(v) : f2h(v);
    }
  }
}

// ---------------- K3: gather attention (f16 dot2 QmK, readlane, XCD swizzle) ------
__global__ __launch_bounds__(256) void k_attn(const unsigned short* __restrict__ qh,
    const unsigned short* __restrict__ ksw, const unsigned short* __restrict__ vsw,
    const int* __restrict__ widx, const float* __restrict__ dprob,
    const float* __restrict__ kpe, const float* __restrict__ vpe,
    const float* __restrict__ rpe, unsigned short* __restrict__ aoutb) {
  int lane = threadIdx.x & 63;
  int wave = threadIdx.x >> 6;
  int bid = blockIdx.x;
  int n = (bid >> 1) & 3;
  int within = ((bid >> 3) << 1) | (bid & 1);
  int token = n * HW + within * 4 + wave;
  const unsigned short* Kb = ksw + (size_t)n * HW * C;
  const unsigned short* Vb = vsw + (size_t)n * HW * C;
  int g = lane >> 3, s = lane & 7;
  int myidx = widx[token * D + lane];
  float mydp = dprob[token * D + lane];
  // Q segment (f16): channels [s*16, s*16+16) as 8 half2
  half2v qreg[8];
  {
    const unsigned short* qp = qh + (size_t)token * C + s * 16;
    U4H qa, qb2;
    qa.v = *(const uint4*)(qp);
    qb2.v = *(const uint4*)(qp + 8);
    #pragma unroll
    for (int i = 0; i < 4; i++) { qreg[i] = qa.h[i]; qreg[4 + i] = qb2.h[i]; }
  }
  half2v ones = {(_Float16)1.0f, (_Float16)1.0f};
  float qpe = 0.f;
  #pragma unroll
  for (int i = 0; i < 8; i++) qpe = dot2h(qreg[i], ones, qpe);
  qpe += __shfl_xor(qpe, 1, 64);
  qpe += __shfl_xor(qpe, 2, 64);
  qpe += __shfl_xor(qpe, 4, 64);
  // QmK: hoist 8 row indices, then all 16 loads (MLP), then dot2 compute
  int rowv[8];
  #pragma unroll
  for (int pass = 0; pass < 8; ++pass)
    rowv[pass] = __shfl(myidx, pass * 8 + g, 64);
  uint4 ka[8], kb[8];
  #pragma unroll
  for (int pass = 0; pass < 8; ++pass) {
    const unsigned short* kr = Kb + (size_t)rowv[pass] * C + s * 16;
    ka[pass] = *(const uint4*)(kr);
    kb[pass] = *(const uint4*)(kr + 8);
  }
  float mycost = 0.f;
  #pragma unroll
  for (int pass = 0; pass < 8; ++pass) {
    U4H ua, ub;
    ua.v = ka[pass]; ub.v = kb[pass];
    float p = 0.f;
    #pragma unroll
    for (int i = 0; i < 4; i++) p = dot2h(ua.h[i], qreg[i], p);
    #pragma unroll
    for (int i = 0; i < 4; i++) p = dot2h(ub.h[i], qreg[4 + i], p);
    p += __shfl_xor(p, 1, 64);
    p += __shfl_xor(p, 2, 64);
    p += __shfl_xor(p, 4, 64);
    float t = __shfl(p, (lane & 7) << 3, 64);
    if (pass == g) mycost = t;
  }
  mycost += qpe * kpe[lane] + rpe[lane];
  float mx = mycost;
  for (int off = 32; off; off >>= 1) mx = fmaxf(mx, __shfl_xor(mx, off, 64));
  float e = __expf(mycost - mx);
  float ssum = e;
  for (int off = 32; off; off >>= 1) ssum += __shfl_xor(ssum, off, 64);
  float attn = (e / ssum) * mydp;
  float s2 = attn;
  for (int off = 32; off; off >>= 1) s2 += __shfl_xor(s2, off, 64);
  attn = (attn + EPS_R) / (s2 + EPS_R);
  float vpt = attn * vpe[lane];
  for (int off = 32; off; off >>= 1) vpt += __shfl_xor(vpt, off, 64);
  // AmV: batches of 8 loads in flight, readlane broadcasts (V bf16)
  float o0 = vpt, o1 = vpt;
  unsigned att_u = __float_as_uint(attn);
  #pragma unroll
  for (int blk = 0; blk < 8; ++blk) {
    unsigned vv[8];
    #pragma unroll
    for (int j = 0; j < 8; j++) {
      int row = __builtin_amdgcn_readlane(myidx, blk * 8 + j);
      vv[j] = *(const unsigned*)(Vb + (size_t)row * C + lane * 2);
    }
    #pragma unroll
    for (int j = 0; j < 8; j++) {
      float a = __uint_as_float(__builtin_amdgcn_readlane(att_u, blk * 8 + j));
      o0 += a * bflo(vv[j]);
      o1 += a * bfhi(vv[j]);
    }
  }
  unsigned pk = (unsigned)f2bf(o0) | ((unsigned)f2bf(o1) << 16);
  *(unsigned*)(aoutb + (size_t)token * C + lane * 2) = pk;
}

// ---------------- K4: proj GEMM + residual(from feat, transposed) + LN2 -----------
__global__ __launch_bounds__(256) void k_projln(const unsigned short* __restrict__ aoutb,
    const unsigned short* __restrict__ wt, const float* __restrict__ pb,
    const float* __restrict__ feat, float* __restrict__ xio,
    const float* __restrict__ g2, const float* __restrict__ b2,
    unsigned short* __restrict__ xn2b) {
  int w = threadIdx.x >> 6, lane = threadIdx.x & 63;
  int q4 = lane >> 4, m = lane & 15;
  int t0 = blockIdx.x * 64 + w * 16;
  const unsigned short* Wt = wt + 3 * 16384;  // pwT
  const unsigned short* ap = aoutb + (size_t)(t0 + m) * C + q4 * 8;
  bf16x8 a[4];
  #pragma unroll
  for (int ks = 0; ks < 4; ks++) a[ks] = *(const bf16x8*)(ap + ks * 32);
  f32x4 acc[8];
  #pragma unroll
  for (int nt = 0; nt < 8; nt++) acc[nt] = (f32x4){0.f, 0.f, 0.f, 0.f};
  #pragma unroll
  for (int nt = 0; nt < 8; nt++) {
    const unsigned short* bp = Wt + (size_t)(nt * 16 + m) * C + q4 * 8;
    #pragma unroll
    for (int ks = 0; ks < 4; ks++) {
      bf16x8 bfrag = *(const bf16x8*)(bp + ks * 32);
      acc[nt] = MFMA16(a[ks], bfrag, acc[nt]);
    }
  }
  int nview = t0 >> 12, ibase = (t0 & 4095) + q4 * 4;
  float s1[4] = {0.f, 0.f, 0.f, 0.f}, s2[4] = {0.f, 0.f, 0.f, 0.f};
  #pragma unroll
  for (int nt = 0; nt < 8; nt++) {
    int col = nt * 16 + m;
    float bb = pb[col];
    const float* fp = feat + ((size_t)nview * C + col) * HW + ibase;
    #pragma unroll
    for (int reg = 0; reg < 4; reg++) {
      float v = acc[nt][reg] + bb + fp[reg];
      acc[nt][reg] = v;
      s1[reg] += v;
      s2[reg] += v * v;
    }
  }
  #pragma unroll
  for (int reg = 0; reg < 4; reg++) {
    #pragma unroll
    for (int off = 1; off < 16; off <<= 1) {
      s1[reg] += __shfl_xor(s1[reg], off, 64);
      s2[reg] += __shfl_xor(s2[reg], off, 64);
    }
  }
  float mean[4], rstd[4];
  #pragma unroll
  for (int reg = 0; reg < 4; reg++) {
    mean[reg] = s1[reg] * (1.0f / 128.0f);
    float var = s2[reg] * (1.0f / 128.0f) - mean[reg] * mean[reg];
    rstd[reg] = rsqrtf(var + LN_EPS);
  }
  #pragma unroll
  for (int nt = 0; nt < 8; nt++) {
    int col = nt * 16 + m;
    float gc = g2[col], bc = b2[col];
    #pragma unroll
    for (int reg = 0; reg < 4; reg++) {
      int row = t0 + q4 * 4 + reg;
      float v = acc[nt][reg];
      xio[(size_t)row * C + col] = v;
      xn2b[(size_t)row * C + col] = f2bf((v - mean[reg]) * rstd[reg] * gc + bc);
    }
  }
}

// ---------------- K5: fc1 GEMM (MFMA, y-split x2) + GELU -> bf16 ------------------
__global__ __launch_bounds__(256) void k_fc1(const unsigned short* __restrict__ xn2b,
    const unsigned short* __restrict__ wt, const float* __restrict__ f1b,
    unsigned short* __restrict__ y) {
  int w = threadIdx.x >> 6, lane = threadIdx.x & 63;
  int q4 = lane >> 4, m = lane & 15;
  int t0 = blockIdx.x * 64 + w * 16;
  int n0 = blockIdx.y * 128;
  const unsigned short* Wt = wt + 65536 + (size_t)n0 * C;
  const unsigned short* ap = xn2b + (size_t)(t0 + m) * C + q4 * 8;
  bf16x8 a[4];
  #pragma unroll
  for (int ks = 0; ks < 4; ks++) a[ks] = *(const bf16x8*)(ap + ks * 32);
  f32x4 acc[8];
  #pragma unroll
  for (int nt = 0; nt < 8; nt++) acc[nt] = (f32x4){0.f, 0.f, 0.f, 0.f};
  #pragma unroll
  for (int nt = 0; nt < 8; nt++) {
    const unsigned short* bp = Wt + (size_t)(nt * 16 + m) * C + q4 * 8;
    #pragma unroll
    for (int ks = 0; ks < 4; ks++) {
      bf16x8 bfrag = *(const bf16x8*)(bp + ks * 32);
      acc[nt] = MFMA16(a[ks], bfrag, acc[nt]);
    }
  }
  #pragma unroll
  for (int nt = 0; nt < 8; nt++) {
    int col = n0 + nt * 16 + m;
    float bb = f1b[col];
    #pragma unroll
    for (int reg = 0; reg < 4; reg++) {
      int row = t0 + q4 * 4 + reg;
      y[(size_t)row * HID + col] = f2bf(gelu_exact(acc[nt][reg] + bb));
    }
  }
}

// ---------------- K6: depthwise 5x5 conv + GELU; writes ysum = y + yc -------------
__global__ __launch_bounds__(256) void k_dwconv(const unsigned short* __restrict__ y,
    const float* __restrict__ w, const float* __restrict__ bias,
    unsigned short* __restrict__ ysum) {
  __shared__ float tile[8][401];   // [channel][spatial 20x20], odd stride
  __shared__ float wl[8][25];
  __shared__ float bl[8];
  int bid = blockIdx.x;
  int tile_id = bid & 15;
  int cb = (bid >> 4) & 31;
  int n = bid >> 9;
  int ty = (tile_id >> 2) * 16, tx = (tile_id & 3) * 16;
  int ch0 = cb * 8;
  int tid = threadIdx.x;
  if (tid < 200) wl[tid / 25][tid % 25] = w[(size_t)(ch0 + tid / 25) * 25 + tid % 25];
  if (tid < 8) bl[tid] = bias[ch0 + tid];
  const unsigned short* yb = y + (size_t)n * HW * HID;
  // staging: one uint4 (8 ch x bf16) per pixel
  for (int p = tid; p < 400; p += 256) {
    int py = p / 20, px = p % 20;
    int gy = ty + py - 2, gx = tx + px - 2;
    uint4 v = make_uint4(0u, 0u, 0u, 0u);
    if (gy >= 0 && gy < 64 && gx >= 0 && gx < 64)
      v = *(const uint4*)(yb + (size_t)(gy * 64 + gx) * HID + ch0);
    tile[0][p] = bflo(v.x); tile[1][p] = bfhi(v.x);
    tile[2][p] = bflo(v.y); tile[3][p] = bfhi(v.y);
    tile[4][p] = bflo(v.z); tile[5][p] = bfhi(v.z);
    tile[6][p] = bflo(v.w); tile[7][p] = bfhi(v.w);
  }
  __syncthreads();
  int cc = tid & 7;
  int xx = (tid >> 3) & 15;
  int yg = tid >> 7;
  float wreg[25];
  #pragma unroll
  for (int k = 0; k < 25; k++) wreg[k] = wl[cc][k];
  float bb = bl[cc];
  float win[12][5];
  #pragma unroll
  for (int r = 0; r < 12; r++)
    #pragma unroll
    for (int dx = 0; dx < 5; dx++)
      win[r][dx] = tile[cc][(yg * 8 + r) * 20 + xx + dx];
  #pragma unroll
  for (int j = 0; j < 8; ++j) {
    float acc = 0.f;
    #pragma unroll
    for (int dy = 0; dy < 5; ++dy)
      #pragma unroll
      for (int dx = 0; dx < 5; ++dx)
        acc += wreg[dy * 5 + dx] * win[j + dy][dx];
    // ysum = y(center) + gelu(conv + bias)
    float o = win[j + 2][2] + gelu_exact(acc + bb);
    int yy = yg * 8 + j;
    ysum[(size_t)(n * HW + (ty + yy) * 64 + tx + xx) * HID + ch0 + cc] = f2bf(o);
  }
}

// ---------------- K7: fc2 GEMM (MFMA, col-split x2) on ysum + residual ------------
__global__ __launch_bounds__(256) void k_fc2(const unsigned short* __restrict__ ysum,
    const unsigned short* __restrict__ wt, const float* __restrict__ f2b,
    const float* __restrict__ xio, float* __restrict__ outp) {
  int w = threadIdx.x >> 6, lane = threadIdx.x & 63;
  int q4 = lane >> 4, m = lane & 15;
  int t0 = blockIdx.x * 64 + w * 16;
  int half = blockIdx.y;
  const unsigned short* Wt = wt + 98304;  // f2wT [128][256]
  const unsigned short* ap = ysum + (size_t)(t0 + m) * HID + q4 * 8;
  bf16x8 a[8];
  #pragma unroll
  for (int ks = 0; ks < 8; ks++) a[ks] = *(const bf16x8*)(ap + ks * 32);
  f32x4 acc[4];
  #pragma unroll
  for (int nt = 0; nt < 4; nt++) acc[nt] = (f32x4){0.f, 0.f, 0.f, 0.f};
  #pragma unroll
  for (int nt = 0; nt < 4; nt++) {
    const unsigned short* bp = Wt + (size_t)(half * 64 + nt * 16 + m) * HID + q4 * 8;
    #pragma unroll
    for (int ks = 0; ks < 8; ks++) {
      bf16x8 bfrag = *(const bf16x8*)(bp + ks * 32);
      acc[nt] = MFMA16(a[ks], bfrag, acc[nt]);
    }
  }
  #pragma unroll
  for (int nt = 0; nt < 4; nt++) {
    int col = half * 64 + nt * 16 + m;
    float bb = f2b[col];
    #pragma unroll
    for (int reg = 0; reg < 4; reg++) {
      int row = t0 + q4 * 4 + reg;
      outp[(size_t)row * C + col] = acc[nt][reg] + bb + xio[(size_t)row * C + col];
    }
  }
}

extern "C" void kernel_launch(void* const* d_in, const int* in_sizes, int n_in,
                              void* d_out, int out_size, void* d_ws, size_t ws_size,
                              hipStream_t stream) {
  (void)in_sizes; (void)n_in; (void)out_size; (void)ws_size;
  const float* feat  = (const float*)d_in[0];
  const int*   widx  = (const int*)d_in[1];
  const float* dprob = (const float*)d_in[2];
  const float* ln1g  = (const float*)d_in[3];
  const float* ln1b  = (const float*)d_in[4];
  const float* wq    = (const float*)d_in[5];
  const float* bq    = (const float*)d_in[6];
  const float* wk    = (const float*)d_in[7];
  const float* bk    = (const float*)d_in[8];
  const float* wv    = (const float*)d_in[9];
  const float* bv    = (const float*)d_in[10];
  const float* kpe   = (const float*)d_in[11];
  const float* vpe   = (const float*)d_in[12];
  const float* rpe   = (const float*)d_in[13];
  const float* pw    = (const float*)d_in[14];
  const float* pb    = (const float*)d_in[15];
  const float* ln2g  = (const float*)d_in[16];
  const float* ln2b  = (const float*)d_in[17];
  const float* f1w   = (const float*)d_in[18];
  const float* f1b   = (const float*)d_in[19];
  const float* dww   = (const float*)d_in[20];
  const float* dwb   = (const float*)d_in[21];
  const float* f2w   = (const float*)d_in[22];
  const float* f2b   = (const float*)d_in[23];

  float* ws = (float*)d_ws;
  const size_t M2 = (size_t)TOK * C;  // 2,097,152 floats (8 MB)
  float* xio = ws;                                                   // fp32 residual stream
  unsigned short* qhb   = (unsigned short*)(ws + M2);                // f16 q (scaled)
  unsigned short* xnb   = (unsigned short*)(ws + M2 + M2 / 2);       // bf16 ln1 out
  unsigned short* ksb   = (unsigned short*)(ws + 2 * M2);            // f16 K (swapped)
  unsigned short* vsb   = (unsigned short*)(ws + 2 * M2 + M2 / 2);   // bf16 V (swapped)
  unsigned short* aoutb = (unsigned short*)(ws + 3 * M2);            // bf16 attn out
  unsigned short* xn2b  = (unsigned short*)(ws + 3 * M2 + M2 / 2);   // bf16 ln2 out
  unsigned short* yb    = (unsigned short*)(ws + 4 * M2);            // bf16 fc1 out (2*M2 ush)
  unsigned short* ysumb = (unsigned short*)(ws + 5 * M2);            // bf16 y+yc (2*M2 ush)
  unsigned short* wtb   = (unsigned short*)(ws + 6 * M2);            // bf16 weights (131072 ush)

  k_prep  <<<512, 256, 0, stream>>>(wq, wk, wv, pw, f1w, f2w, wtb);
  k_ln1   <<<TOK / 64, 256, 0, stream>>>(feat, ln1g, ln1b, xnb);
  k_qkv   <<<dim3(TOK / 64, 3), 256, 0, stream>>>(xnb, wtb, bq, bk, bv, qhb, ksb, vsb);
  k_attn  <<<TOK / 4, 256, 0, stream>>>(qhb, ksb, vsb, widx, dprob, kpe, vpe, rpe, aoutb);
  k_projln<<<TOK / 64, 256, 0, stream>>>(aoutb, wtb, pb, feat, xio, ln2g, ln2b, xn2b);
  k_fc1   <<<dim3(TOK / 64, 2), 256, 0, stream>>>(xn2b, wtb, f1b, yb);
  k_dwconv<<<2048, 256, 0, stream>>>(yb, dww, dwb, ysumb);
  k_fc2   <<<dim3(TOK / 64, 2), 256, 0, stream>>>(ysumb, wtb, f2b, xio, (float*)d_out);
}

// Round 9
// 207.620 us; speedup vs baseline: 1.1143x; 1.0161x over previous
//
#include <hip/hip_runtime.h>
#include <math.h>

#define TOK   16384   // Bf * hw
#define HW    4096
#define C     128
#define D     64
#define HID   256

constexpr float LN_EPS = 1e-5f;
constexpr float EPS_R  = 1e-10f;
constexpr float QSCALE = 0.08838834764831845f; // 128^-0.5

typedef __attribute__((ext_vector_type(8))) short  bf16x8;
typedef __attribute__((ext_vector_type(4))) float  f32x4;
typedef __attribute__((ext_vector_type(2))) _Float16 half2v;
#define MFMA16(a, b, c) __builtin_amdgcn_mfma_f32_16x16x32_bf16((a), (b), (c), 0, 0, 0)

__device__ __forceinline__ float bflo(unsigned u) { return __uint_as_float(u << 16); }
__device__ __forceinline__ float bfhi(unsigned u) { return __uint_as_float(u & 0xffff0000u); }
__device__ __forceinline__ float bfu(unsigned short u) { return __uint_as_float((unsigned)u << 16); }
__device__ __forceinline__ unsigned short f2bf(float f) {
  unsigned u = __float_as_uint(f);
  unsigned r = (u + 0x7fffu + ((u >> 16) & 1u)) >> 16;
  return (unsigned short)r;
}
__device__ __forceinline__ unsigned short f2h(float f) {
  _Float16 h = (_Float16)f;
  unsigned short r;
  __builtin_memcpy(&r, &h, 2);
  return r;
}
__device__ __forceinline__ float gelu_exact(float x) {
  return 0.5f * x * (1.0f + erff(x * 0.7071067811865476f));
}

union U4H { uint4 v; half2v h[4]; };
union U1H { unsigned v; half2v h; };

#if __has_builtin(__builtin_amdgcn_fdot2)
__device__ __forceinline__ float dot2h(half2v a, half2v b, float c) {
  return __builtin_amdgcn_fdot2(a, b, c, false);
}
#else
__device__ __forceinline__ float dot2h(half2v a, half2v b, float c) {
  return c + (float)a.x * (float)b.x + (float)a.y * (float)b.y;
}
#endif

// ---------------- K1: fused [weight prep | transpose + LN1] -----------------------
// blocks [0,512): prep weights -> bf16 transposed. blocks [512,768): LN1.
__global__ __launch_bounds__(256) void k_prepln1(const float* __restrict__ wq,
    const float* __restrict__ wk, const float* __restrict__ wv,
    const float* __restrict__ pw, const float* __restrict__ f1w,
    const float* __restrict__ f2w, unsigned short* __restrict__ wt,
    const float* __restrict__ feat, const float* __restrict__ g,
    const float* __restrict__ b, unsigned short* __restrict__ xnb) {
  __shared__ float tile[64][C + 1];
  int bidx = blockIdx.x;
  if (bidx < 512) {
    int id = bidx * 256 + threadIdx.x;
    if (id < 16384) {
      int n = id >> 7, k = id & 127;
      wt[id] = f2bf(wq[k * 128 + n]);
    } else if (id < 32768) {
      int e = id - 16384; int n = e >> 7, k = e & 127;
      wt[id] = f2bf(wk[k * 128 + n]);
    } else if (id < 49152) {
      int e = id - 32768; int n = e >> 7, k = e & 127;
      wt[id] = f2bf(wv[k * 128 + n]);
    } else if (id < 65536) {
      int e = id - 49152; int n = e >> 7, k = e & 127;
      wt[id] = f2bf(pw[k * 128 + n]);
    } else if (id < 98304) {
      int e = id - 65536; int n = e >> 7, k = e & 127;
      wt[id] = f2bf(f1w[k * 256 + n]);
    } else {
      int e = id - 98304; int n = e >> 8, k = e & 255;
      wt[id] = f2bf(f2w[k * 128 + n]);
    }
    return;
  }
  int t0 = (bidx - 512) * 64;
  int n = t0 / HW, i0 = t0 % HW;
  int tid = threadIdx.x;
  const float* fb = feat + (size_t)n * C * HW;
  for (int e = tid; e < 64 * C; e += 256) {
    int ch = e >> 6, ii = e & 63;
    tile[ii][ch] = fb[(size_t)ch * HW + i0 + ii];
  }
  __syncthreads();
  int wave = tid >> 6, lane = tid & 63;
  for (int tkn = wave; tkn < 64; tkn += 4) {
    float a0 = tile[tkn][lane];
    float a1 = tile[tkn][lane + 64];
    float s = a0 + a1;
    for (int off = 32; off; off >>= 1) s += __shfl_xor(s, off, 64);
    float mean = s * (1.0f / 128.0f);
    float d0 = a0 - mean, d1 = a1 - mean;
    float v = d0 * d0 + d1 * d1;
    for (int off = 32; off; off >>= 1) v += __shfl_xor(v, off, 64);
    float rstd = rsqrtf(v * (1.0f / 128.0f) + LN_EPS);
    size_t ro = (size_t)(t0 + tkn) * C;
    xnb[ro + lane]      = f2bf(d0 * rstd * g[lane] + b[lane]);
    xnb[ro + lane + 64] = f2bf(d1 * rstd * g[lane + 64] + b[lane + 64]);
  }
}

// ---------------- K2: QKV GEMM via MFMA; Q,K,V out fp16 ---------------------------
__global__ __launch_bounds__(256) void k_qkv(const unsigned short* __restrict__ xnb,
    const unsigned short* __restrict__ wt,
    const float* __restrict__ bq, const float* __restrict__ bk,
    const float* __restrict__ bv, unsigned short* __restrict__ qh,
    unsigned short* __restrict__ ksw, unsigned short* __restrict__ vsw) {
  int w = threadIdx.x >> 6, lane = threadIdx.x & 63;
  int q4 = lane >> 4, m = lane & 15;
  int t0 = blockIdx.x * 64 + w * 16;
  int wsel = blockIdx.y;
  const unsigned short* Wt = wt + wsel * 16384;
  const unsigned short* ap = xnb + (size_t)(t0 + m) * C + q4 * 8;
  bf16x8 a[4];
  #pragma unroll
  for (int ks = 0; ks < 4; ks++) a[ks] = *(const bf16x8*)(ap + ks * 32);
  f32x4 acc[8];
  #pragma unroll
  for (int nt = 0; nt < 8; nt++) acc[nt] = (f32x4){0.f, 0.f, 0.f, 0.f};
  #pragma unroll
  for (int nt = 0; nt < 8; nt++) {
    const unsigned short* bp = Wt + (size_t)(nt * 16 + m) * C + q4 * 8;
    #pragma unroll
    for (int ks = 0; ks < 4; ks++) {
      bf16x8 bfrag = *(const bf16x8*)(bp + ks * 32);
      acc[nt] = MFMA16(a[ks], bfrag, acc[nt]);
    }
  }
  const float* B = (wsel == 0) ? bq : ((wsel == 1) ? bk : bv);
  float sc = (wsel == 0) ? QSCALE : 1.0f;
  unsigned short* O = (wsel == 0) ? qh : ((wsel == 1) ? ksw : vsw);
  int n = t0 >> 12, i0 = t0 & 4095;
  int base = (wsel == 0) ? t0 : (((n ^ 1) << 12) + i0);
  #pragma unroll
  for (int nt = 0; nt < 8; nt++) {
    int col = nt * 16 + m;
    float bb = B[col];
    #pragma unroll
    for (int reg = 0; reg < 4; reg++) {
      int row = base + q4 * 4 + reg;
      O[(size_t)row * C + col] = f2h((acc[nt][reg] + bb) * sc);
    }
  }
}

// ---------------- K3: gather attention (f16 dot2 QmK, fma_mix AmV) ----------------
__global__ __launch_bounds__(256) void k_attn(const unsigned short* __restrict__ qh,
    const unsigned short* __restrict__ ksw, const unsigned short* __restrict__ vsw,
    const int* __restrict__ widx, const float* __restrict__ dprob,
    const float* __restrict__ kpe, const float* __restrict__ vpe,
    const float* __restrict__ rpe, unsigned short* __restrict__ aoutb) {
  int lane = threadIdx.x & 63;
  int wave = threadIdx.x >> 6;
  int bid = blockIdx.x;
  int n = (bid >> 1) & 3;
  int within = ((bid >> 3) << 1) | (bid & 1);
  int token = n * HW + within * 4 + wave;
  const unsigned short* Kb = ksw + (size_t)n * HW * C;
  const unsigned short* Vb = vsw + (size_t)n * HW * C;
  int g = lane >> 3, s = lane & 7;
  int myidx = widx[token * D + lane];
  float mydp = dprob[token * D + lane];
  // Q segment (f16): channels [s*16, s*16+16) as 8 half2
  half2v qreg[8];
  {
    const unsigned short* qp = qh + (size_t)token * C + s * 16;
    U4H qa, qb2;
    qa.v = *(const uint4*)(qp);
    qb2.v = *(const uint4*)(qp + 8);
    #pragma unroll
    for (int i = 0; i < 4; i++) { qreg[i] = qa.h[i]; qreg[4 + i] = qb2.h[i]; }
  }
  half2v ones = {(_Float16)1.0f, (_Float16)1.0f};
  float qpe = 0.f;
  #pragma unroll
  for (int i = 0; i < 8; i++) qpe = dot2h(qreg[i], ones, qpe);
  qpe += __shfl_xor(qpe, 1, 64);
  qpe += __shfl_xor(qpe, 2, 64);
  qpe += __shfl_xor(qpe, 4, 64);
  // QmK: hoist 8 row indices, then all 16 loads (MLP), then dot2 compute
  int rowv[8];
  #pragma unroll
  for (int pass = 0; pass < 8; ++pass)
    rowv[pass] = __shfl(myidx, pass * 8 + g, 64);
  uint4 ka[8], kb[8];
  #pragma unroll
  for (int pass = 0; pass < 8; ++pass) {
    const unsigned short* kr = Kb + (size_t)rowv[pass] * C + s * 16;
    ka[pass] = *(const uint4*)(kr);
    kb[pass] = *(const uint4*)(kr + 8);
  }
  float mycost = 0.f;
  #pragma unroll
  for (int pass = 0; pass < 8; ++pass) {
    U4H ua, ub;
    ua.v = ka[pass]; ub.v = kb[pass];
    float p = 0.f;
    #pragma unroll
    for (int i = 0; i < 4; i++) p = dot2h(ua.h[i], qreg[i], p);
    #pragma unroll
    for (int i = 0; i < 4; i++) p = dot2h(ub.h[i], qreg[4 + i], p);
    p += __shfl_xor(p, 1, 64);
    p += __shfl_xor(p, 2, 64);
    p += __shfl_xor(p, 4, 64);
    float t = __shfl(p, (lane & 7) << 3, 64);
    if (pass == g) mycost = t;
  }
  mycost += qpe * kpe[lane] + rpe[lane];
  float mx = mycost;
  for (int off = 32; off; off >>= 1) mx = fmaxf(mx, __shfl_xor(mx, off, 64));
  float e = __expf(mycost - mx);
  float ssum = e;
  for (int off = 32; off; off >>= 1) ssum += __shfl_xor(ssum, off, 64);
  float attn = (e / ssum) * mydp;
  float s2 = attn;
  for (int off = 32; off; off >>= 1) s2 += __shfl_xor(s2, off, 64);
  attn = (attn + EPS_R) / (s2 + EPS_R);
  float vpt = attn * vpe[lane];
  for (int off = 32; off; off >>= 1) vpt += __shfl_xor(vpt, off, 64);
  // AmV: batches of 8 loads in flight; V fp16 -> v_fma_mix (no unpack)
  float o0 = vpt, o1 = vpt;
  unsigned att_u = __float_as_uint(attn);
  #pragma unroll
  for (int blk = 0; blk < 8; ++blk) {
    unsigned vv[8];
    #pragma unroll
    for (int j = 0; j < 8; j++) {
      int row = __builtin_amdgcn_readlane(myidx, blk * 8 + j);
      vv[j] = *(const unsigned*)(Vb + (size_t)row * C + lane * 2);
    }
    #pragma unroll
    for (int j = 0; j < 8; j++) {
      float a = __uint_as_float(__builtin_amdgcn_readlane(att_u, blk * 8 + j));
      U1H h; h.v = vv[j];
      o0 += a * (float)h.h.x;   // v_fma_mix_f32
      o1 += a * (float)h.h.y;
    }
  }
  unsigned pk = (unsigned)f2bf(o0) | ((unsigned)f2bf(o1) << 16);
  *(unsigned*)(aoutb + (size_t)token * C + lane * 2) = pk;
}

// ---------------- K4: proj GEMM + residual(from feat, transposed) + LN2 -----------
__global__ __launch_bounds__(256) void k_projln(const unsigned short* __restrict__ aoutb,
    const unsigned short* __restrict__ wt, const float* __restrict__ pb,
    const float* __restrict__ feat, float* __restrict__ xio,
    const float* __restrict__ g2, const float* __restrict__ b2,
    unsigned short* __restrict__ xn2b) {
  int w = threadIdx.x >> 6, lane = threadIdx.x & 63;
  int q4 = lane >> 4, m = lane & 15;
  int t0 = blockIdx.x * 64 + w * 16;
  const unsigned short* Wt = wt + 3 * 16384;  // pwT
  const unsigned short* ap = aoutb + (size_t)(t0 + m) * C + q4 * 8;
  bf16x8 a[4];
  #pragma unroll
  for (int ks = 0; ks < 4; ks++) a[ks] = *(const bf16x8*)(ap + ks * 32);
  f32x4 acc[8];
  #pragma unroll
  for (int nt = 0; nt < 8; nt++) acc[nt] = (f32x4){0.f, 0.f, 0.f, 0.f};
  #pragma unroll
  for (int nt = 0; nt < 8; nt++) {
    const unsigned short* bp = Wt + (size_t)(nt * 16 + m) * C + q4 * 8;
    #pragma unroll
    for (int ks = 0; ks < 4; ks++) {
      bf16x8 bfrag = *(const bf16x8*)(bp + ks * 32);
      acc[nt] = MFMA16(a[ks], bfrag, acc[nt]);
    }
  }
  int nview = t0 >> 12, ibase = (t0 & 4095) + q4 * 4;
  float s1[4] = {0.f, 0.f, 0.f, 0.f}, s2[4] = {0.f, 0.f, 0.f, 0.f};
  #pragma unroll
  for (int nt = 0; nt < 8; nt++) {
    int col = nt * 16 + m;
    float bb = pb[col];
    const float* fp = feat + ((size_t)nview * C + col) * HW + ibase;
    #pragma unroll
    for (int reg = 0; reg < 4; reg++) {
      float v = acc[nt][reg] + bb + fp[reg];
      acc[nt][reg] = v;
      s1[reg] += v;
      s2[reg] += v * v;
    }
  }
  #pragma unroll
  for (int reg = 0; reg < 4; reg++) {
    #pragma unroll
    for (int off = 1; off < 16; off <<= 1) {
      s1[reg] += __shfl_xor(s1[reg], off, 64);
      s2[reg] += __shfl_xor(s2[reg], off, 64);
    }
  }
  float mean[4], rstd[4];
  #pragma unroll
  for (int reg = 0; reg < 4; reg++) {
    mean[reg] = s1[reg] * (1.0f / 128.0f);
    float var = s2[reg] * (1.0f / 128.0f) - mean[reg] * mean[reg];
    rstd[reg] = rsqrtf(var + LN_EPS);
  }
  #pragma unroll
  for (int nt = 0; nt < 8; nt++) {
    int col = nt * 16 + m;
    float gc = g2[col], bc = b2[col];
    #pragma unroll
    for (int reg = 0; reg < 4; reg++) {
      int row = t0 + q4 * 4 + reg;
      float v = acc[nt][reg];
      xio[(size_t)row * C + col] = v;
      xn2b[(size_t)row * C + col] = f2bf((v - mean[reg]) * rstd[reg] * gc + bc);
    }
  }
}

// ---------------- K5: fc1 GEMM (MFMA, y-split x2) + GELU -> bf16 ------------------
__global__ __launch_bounds__(256) void k_fc1(const unsigned short* __restrict__ xn2b,
    const unsigned short* __restrict__ wt, const float* __restrict__ f1b,
    unsigned short* __restrict__ y) {
  int w = threadIdx.x >> 6, lane = threadIdx.x & 63;
  int q4 = lane >> 4, m = lane & 15;
  int t0 = blockIdx.x * 64 + w * 16;
  int n0 = blockIdx.y * 128;
  const unsigned short* Wt = wt + 65536 + (size_t)n0 * C;
  const unsigned short* ap = xn2b + (size_t)(t0 + m) * C + q4 * 8;
  bf16x8 a[4];
  #pragma unroll
  for (int ks = 0; ks < 4; ks++) a[ks] = *(const bf16x8*)(ap + ks * 32);
  f32x4 acc[8];
  #pragma unroll
  for (int nt = 0; nt < 8; nt++) acc[nt] = (f32x4){0.f, 0.f, 0.f, 0.f};
  #pragma unroll
  for (int nt = 0; nt < 8; nt++) {
    const unsigned short* bp = Wt + (size_t)(nt * 16 + m) * C + q4 * 8;
    #pragma unroll
    for (int ks = 0; ks < 4; ks++) {
      bf16x8 bfrag = *(const bf16x8*)(bp + ks * 32);
      acc[nt] = MFMA16(a[ks], bfrag, acc[nt]);
    }
  }
  #pragma unroll
  for (int nt = 0; nt < 8; nt++) {
    int col = n0 + nt * 16 + m;
    float bb = f1b[col];
    #pragma unroll
    for (int reg = 0; reg < 4; reg++) {
      int row = t0 + q4 * 4 + reg;
      y[(size_t)row * HID + col] = f2bf(gelu_exact(acc[nt][reg] + bb));
    }
  }
}

// ---------------- K6: depthwise 5x5 conv + GELU; writes ysum = y + yc -------------
__global__ __launch_bounds__(256) void k_dwconv(const unsigned short* __restrict__ y,
    const float* __restrict__ w, const float* __restrict__ bias,
    unsigned short* __restrict__ ysum) {
  __shared__ float tile[8][401];   // [channel][spatial 20x20], odd stride
  __shared__ float wl[8][25];
  __shared__ float bl[8];
  int bid = blockIdx.x;
  int tile_id = bid & 15;
  int cb = (bid >> 4) & 31;
  int n = bid >> 9;
  int ty = (tile_id >> 2) * 16, tx = (tile_id & 3) * 16;
  int ch0 = cb * 8;
  int tid = threadIdx.x;
  if (tid < 200) wl[tid / 25][tid % 25] = w[(size_t)(ch0 + tid / 25) * 25 + tid % 25];
  if (tid < 8) bl[tid] = bias[ch0 + tid];
  const unsigned short* yb = y + (size_t)n * HW * HID;
  for (int p = tid; p < 400; p += 256) {
    int py = p / 20, px = p % 20;
    int gy = ty + py - 2, gx = tx + px - 2;
    uint4 v = make_uint4(0u, 0u, 0u, 0u);
    if (gy >= 0 && gy < 64 && gx >= 0 && gx < 64)
      v = *(const uint4*)(yb + (size_t)(gy * 64 + gx) * HID + ch0);
    tile[0][p] = bflo(v.x); tile[1][p] = bfhi(v.x);
    tile[2][p] = bflo(v.y); tile[3][p] = bfhi(v.y);
    tile[4][p] = bflo(v.z); tile[5][p] = bfhi(v.z);
    tile[6][p] = bflo(v.w); tile[7][p] = bfhi(v.w);
  }
  __syncthreads();
  int cc = tid & 7;
  int xx = (tid >> 3) & 15;
  int yg = tid >> 7;
  float wreg[25];
  #pragma unroll
  for (int k = 0; k < 25; k++) wreg[k] = wl[cc][k];
  float bb = bl[cc];
  float win[12][5];
  #pragma unroll
  for (int r = 0; r < 12; r++)
    #pragma unroll
    for (int dx = 0; dx < 5; dx++)
      win[r][dx] = tile[cc][(yg * 8 + r) * 20 + xx + dx];
  #pragma unroll
  for (int j = 0; j < 8; ++j) {
    float acc = 0.f;
    #pragma unroll
    for (int dy = 0; dy < 5; ++dy)
      #pragma unroll
      for (int dx = 0; dx < 5; ++dx)
        acc += wreg[dy * 5 + dx] * win[j + dy][dx];
    float o = win[j + 2][2] + gelu_exact(acc + bb);
    int yy = yg * 8 + j;
    ysum[(size_t)(n * HW + (ty + yy) * 64 + tx + xx) * HID + ch0 + cc] = f2bf(o);
  }
}

// ---------------- K7: fc2 GEMM (MFMA, col-split x2) on ysum + residual ------------
__global__ __launch_bounds__(256) void k_fc2(const unsigned short* __restrict__ ysum,
    const unsigned short* __restrict__ wt, const float* __restrict__ f2b,
    const float* __restrict__ xio, float* __restrict__ outp) {
  int w = threadIdx.x >> 6, lane = threadIdx.x & 63;
  int q4 = lane >> 4, m = lane & 15;
  int t0 = blockIdx.x * 64 + w * 16;
  int half = blockIdx.y;
  const unsigned short* Wt = wt + 98304;  // f2wT [128][256]
  const unsigned short* ap = ysum + (size_t)(t0 + m) * HID + q4 * 8;
  bf16x8 a[8];
  #pragma unroll
  for (int ks = 0; ks < 8; ks++) a[ks] = *(const bf16x8*)(ap + ks * 32);
  f32x4 acc[4];
  #pragma unroll
  for (int nt = 0; nt < 4; nt++) acc[nt] = (f32x4){0.f, 0.f, 0.f, 0.f};
  #pragma unroll
  for (int nt = 0; nt < 4; nt++) {
    const unsigned short* bp = Wt + (size_t)(half * 64 + nt * 16 + m) * HID + q4 * 8;
    #pragma unroll
    for (int ks = 0; ks < 8; ks++) {
      bf16x8 bfrag = *(const bf16x8*)(bp + ks * 32);
      acc[nt] = MFMA16(a[ks], bfrag, acc[nt]);
    }
  }
  #pragma unroll
  for (int nt = 0; nt < 4; nt++) {
    int col = half * 64 + nt * 16 + m;
    float bb = f2b[col];
    #pragma unroll
    for (int reg = 0; reg < 4; reg++) {
      int row = t0 + q4 * 4 + reg;
      outp[(size_t)row * C + col] = acc[nt][reg] + bb + xio[(size_t)row * C + col];
    }
  }
}

extern "C" void kernel_launch(void* const* d_in, const int* in_sizes, int n_in,
                              void* d_out, int out_size, void* d_ws, size_t ws_size,
                              hipStream_t stream) {
  (void)in_sizes; (void)n_in; (void)out_size; (void)ws_size;
  const float* feat  = (const float*)d_in[0];
  const int*   widx  = (const int*)d_in[1];
  const float* dprob = (const float*)d_in[2];
  const float* ln1g  = (const float*)d_in[3];
  const float* ln1b  = (const float*)d_in[4];
  const float* wq    = (const float*)d_in[5];
  const float* bq    = (const float*)d_in[6];
  const float* wk    = (const float*)d_in[7];
  const float* bk    = (const float*)d_in[8];
  const float* wv    = (const float*)d_in[9];
  const float* bv    = (const float*)d_in[10];
  const float* kpe   = (const float*)d_in[11];
  const float* vpe   = (const float*)d_in[12];
  const float* rpe   = (const float*)d_in[13];
  const float* pw    = (const float*)d_in[14];
  const float* pb    = (const float*)d_in[15];
  const float* ln2g  = (const float*)d_in[16];
  const float* ln2b  = (const float*)d_in[17];
  const float* f1w   = (const float*)d_in[18];
  const float* f1b   = (const float*)d_in[19];
  const float* dww   = (const float*)d_in[20];
  const float* dwb   = (const float*)d_in[21];
  const float* f2w   = (const float*)d_in[22];
  const float* f2b   = (const float*)d_in[23];

  float* ws = (float*)d_ws;
  const size_t M2 = (size_t)TOK * C;  // 2,097,152 floats (8 MB)
  float* xio = ws;                                                   // fp32 residual stream
  unsigned short* qhb   = (unsigned short*)(ws + M2);                // f16 q (scaled)
  unsigned short* xnb   = (unsigned short*)(ws + M2 + M2 / 2);       // bf16 ln1 out
  unsigned short* ksb   = (unsigned short*)(ws + 2 * M2);            // f16 K (swapped)
  unsigned short* vsb   = (unsigned short*)(ws + 2 * M2 + M2 / 2);   // f16 V (swapped)
  unsigned short* aoutb = (unsigned short*)(ws + 3 * M2);            // bf16 attn out
  unsigned short* xn2b  = (unsigned short*)(ws + 3 * M2 + M2 / 2);   // bf16 ln2 out
  unsigned short* yb    = (unsigned short*)(ws + 4 * M2);            // bf16 fc1 out (2*M2 ush)
  unsigned short* ysumb = (unsigned short*)(ws + 5 * M2);            // bf16 y+yc (2*M2 ush)
  unsigned short* wtb   = (unsigned short*)(ws + 6 * M2);            // bf16 weights (131072 ush)

  k_prepln1<<<512 + TOK / 64, 256, 0, stream>>>(wq, wk, wv, pw, f1w, f2w, wtb,
                                                feat, ln1g, ln1b, xnb);
  k_qkv   <<<dim3(TOK / 64, 3), 256, 0, stream>>>(xnb, wtb, bq, bk, bv, qhb, ksb, vsb);
  k_attn  <<<TOK / 4, 256, 0, stream>>>(qhb, ksb, vsb, widx, dprob, kpe, vpe, rpe, aoutb);
  k_projln<<<TOK / 64, 256, 0, stream>>>(aoutb, wtb, pb, feat, xio, ln2g, ln2b, xn2b);
  k_fc1   <<<dim3(TOK / 64, 2), 256, 0, stream>>>(xn2b, wtb, f1b, yb);
  k_dwconv<<<2048, 256, 0, stream>>>(yb, dww, dwb, ysumb);
  k_fc2   <<<dim3(TOK / 64, 2), 256, 0, stream>>>(ysumb, wtb, f2b, xio, (float*)d_out);
}